// Round 24
// baseline (132.075 us; speedup 1.0000x reference)
//
#include <hip/hip_runtime.h>
#include <hip/hip_bf16.h>
#include <stdint.h>

#define B_ 2
#define S_ 2048
#define E_ 1024
#define H_ 16
#define DH_ 64
#define MELEMS (4096 * 1024)   // B*S*E
#define WE (1024 * 1024)

typedef unsigned short u16;
typedef __bf16 bf16x8 __attribute__((ext_vector_type(8)));
typedef u16 u16x8 __attribute__((ext_vector_type(8)));
typedef u16 u16x4 __attribute__((ext_vector_type(4)));
typedef float f32x4 __attribute__((ext_vector_type(4)));
typedef float f32x16 __attribute__((ext_vector_type(16)));
typedef uint32_t u32x4 __attribute__((ext_vector_type(4)));
typedef uint32_t u32x2v __attribute__((ext_vector_type(2)));

__device__ __forceinline__ float bf2f(u16 u) {
    union { uint32_t i; float f; } v; v.i = ((uint32_t)u) << 16; return v.f;
}
__device__ __forceinline__ u16 f2bf(float f) {   // RNE fp32->bf16
    union { float f; uint32_t i; } v; v.f = f;
    uint32_t r = (v.i + 0x7FFFu + ((v.i >> 16) & 1u)) >> 16;
    return (u16)r;
}
// single-instruction packed f32x2 -> bf16x2 (RNE, same results as f2bf)
__device__ __forceinline__ uint32_t cvtpk(float a, float b) {
    uint32_t r;
    asm("v_cvt_pk_bf16_f32 %0, %1, %2" : "=v"(r) : "v"(a), "v"(b));
    return r;
}
__device__ __forceinline__ bf16x8 ldfrag(const u16* p) {
    u16x8 t = *(const u16x8*)p;
    return __builtin_bit_cast(bf16x8, t);
}
__device__ __forceinline__ void gld16(const void* g, void* l) {
    __builtin_amdgcn_global_load_lds(
        (const __attribute__((address_space(1))) void*)g,
        (__attribute__((address_space(3))) void*)l, 16, 0, 0);
}

// ---------------------------------------------------------------------------
// Weight transpose only: W[K][N] fp32 -> Wt[N][K] bf16 (LDS-tiled, 65-stride).
// ---------------------------------------------------------------------------
__global__ __launch_bounds__(256)
void cvt_w(const float* __restrict__ W0, const float* __restrict__ W1,
           const float* __restrict__ W2, const float* __restrict__ W3,
           u16* __restrict__ T0, u16* __restrict__ T1,
           u16* __restrict__ T2, u16* __restrict__ T3)
{
    __shared__ float tile[64][65];
    const int rr = blockIdx.x;          // 0..1023
    const int tid = threadIdx.x;
    const int z = rr >> 8;
    const int tt = rr & 255;
    const float* W = (z == 0) ? W0 : (z == 1) ? W1 : (z == 2) ? W2 : W3;
    u16* T = (z == 0) ? T0 : (z == 1) ? T1 : (z == 2) ? T2 : T3;
    const int n0 = (tt & 15) * 64, k0 = (tt >> 4) * 64;
    const int r = tid >> 2, c0 = (tid & 3) * 16;

    #pragma unroll
    for (int i = 0; i < 4; ++i) {
        float4 w = *(const float4*)&W[(size_t)(k0 + r) * 1024 + n0 + c0 + i * 4];
        tile[r][c0 + i * 4 + 0] = w.x; tile[r][c0 + i * 4 + 1] = w.y;
        tile[r][c0 + i * 4 + 2] = w.z; tile[r][c0 + i * 4 + 3] = w.w;
    }
    __syncthreads();
    u16x8 a, b;
    #pragma unroll
    for (int j = 0; j < 8; ++j) a[j] = f2bf(tile[c0 + j][r]);
    #pragma unroll
    for (int j = 0; j < 8; ++j) b[j] = f2bf(tile[c0 + 8 + j][r]);
    *(u16x8*)&T[(size_t)(n0 + r) * 1024 + k0 + c0] = a;
    *(u16x8*)&T[(size_t)(n0 + r) * 1024 + k0 + c0 + 8] = b;
}

// ---------------------------------------------------------------------------
// m97-style GEMM: C = (A[M,K] @ Bt[N,K]^T + bias[N]) * scale.
// AF32=1 (v22-proven): A fp32 fused conversion + DOUBLE-BUFFERED B, counted
//   vmcnt: per iter: lgkmcnt(0)+barrier -> cvtpk A (compiler's A-reg wait
//   drains the OLDER current-B gld16s: B always issued before A) -> issue
//   B(k+32)->Bs[cur^1] -> loadA(k+32) -> ds_write As -> vmcnt(6)+lgkmcnt(0)
//   (6 newest = next-B 2 + next-A 4 in flight; current B older -> landed)
//   -> barrier -> 16 MFMAs.  B-latency cover: full iteration (~800 cyc).
// AF32=0 (v21-proven): double-buffered counted-vmcnt tile staging.
// z==vt_z: writes V^T [B][E][S] with masked key COLUMNS zeroed.
// XCD-chunked block swizzle (T1).
// ---------------------------------------------------------------------------
template<int BN, int AF32>
__global__ __launch_bounds__(256)
void gemm_bt(const void* __restrict__ A0, const void* __restrict__ A1,
             const void* __restrict__ A2,
             const u16* __restrict__ Bt0, const u16* __restrict__ Bt1,
             const u16* __restrict__ Bt2,
             const float* __restrict__ b0, const float* __restrict__ b1,
             const float* __restrict__ b2,
             void* __restrict__ C0, void* __restrict__ C1, void* __restrict__ C2,
             const int* __restrict__ mask,
             int c_f32, int vt_z, float scale0, int K)
{
    const int z = blockIdx.z;
    const void* Av = (z == 0) ? A0 : (z == 1) ? A1 : A2;
    const u16* Bt = (z == 0) ? Bt0 : (z == 1) ? Bt1 : Bt2;
    const float* bias = (z == 0) ? b0 : (z == 1) ? b1 : b2;
    void* C = (z == 0) ? C0 : (z == 1) ? C1 : C2;
    const float scale = (z == 0) ? scale0 : 1.0f;

    // AF32=1: A single-buffered (arrives via regs), B double.  AF32=0: both double.
    __shared__ alignas(16) u16 As[(AF32 ? 1 : 2) * 128 * 32];
    __shared__ alignas(16) u16 Bs[2 * BN * 32];

    const int tid  = threadIdx.x;
    const int lane = tid & 63;
    const int wv   = tid >> 6;
    const int l15  = lane & 15;
    const int quad = lane >> 4;

    // XCD-chunked remap within this z-slice
    const int nwg = gridDim.x * gridDim.y;
    int wg = blockIdx.y * gridDim.x + blockIdx.x;
    wg = (wg & 7) * (nwg >> 3) + (wg >> 3);
    const int bx = wg % gridDim.x;
    const int by = wg / gridDim.x;

    const int m0 = by * 128;
    const int n0 = bx * BN;
    const int wr = (wv >> 1) * 64;
    const int wc = (wv & 1) * (BN / 2);

    const int srow = wv * 16 + (lane >> 2);
    const int skk  = (lane & 3) * 8;

    constexpr int NJ = BN / 32;
    f32x4 acc[4][NJ] = {};

    float4 ar0, ar1, ar2, ar3;      // AF32 staging regs (2 rows x 32B)
    auto loadA = [&](int k0) {
        const float* Af = (const float*)Av;
        const float* p0 = &Af[(size_t)(m0 + srow) * K + k0 + skk];
        const float* p1 = &Af[(size_t)(m0 + 64 + srow) * K + k0 + skk];
        ar0 = *(const float4*)p0;  ar1 = *(const float4*)(p0 + 4);
        ar2 = *(const float4*)p1;  ar3 = *(const float4*)(p1 + 4);
    };
    // stage B tile into buffer `buf` (BN/64 gld16 per thread)
    auto stageB = [&](int k0, int buf) {
        const int bo = buf * (BN * 32);
        #pragma unroll
        for (int h = 0; h < BN / 64; ++h) {
            const int r = h * 64 + srow;
            gld16(&Bt[(size_t)(n0 + r) * K + k0 + skk], &Bs[bo + r * 32 + skk]);
        }
    };
    // AF32=0: stage one full tile (A 2x + B) into buffer `buf`
    auto stageT = [&](int k0, int buf) {
        const u16* Ab = (const u16*)Av;
        const int ao = buf * (128 * 32);
        #pragma unroll
        for (int h = 0; h < 2; ++h) {
            const int r = h * 64 + srow;
            gld16(&Ab[(size_t)(m0 + r) * K + k0 + skk], &As[ao + r * 32 + skk]);
        }
        stageB(k0, buf);
    };

    if (AF32) {
        stageB(0, 0);                 // B first (oldest in FIFO)
        asm volatile("" ::: "memory");
        loadA(0);
        asm volatile("" ::: "memory");
    } else {
        stageT(0, 0);
        asm volatile("" ::: "memory");
    }

    int cur = 0;
    for (int k0 = 0; k0 < K; k0 += 32) {
        if (AF32) {
            // top barrier: ds-reads done; in-flight loads survive
            asm volatile("s_waitcnt lgkmcnt(0)" ::: "memory");
            __builtin_amdgcn_s_barrier();
            asm volatile("" ::: "memory");
            // pack current A; compiler's wait for the A regs also drains the
            // OLDER current-B gld16s (B always issued before A) -> Bs[cur] ok
            u32x4 w0, w1;
            w0[0] = cvtpk(ar0.x, ar0.y); w0[1] = cvtpk(ar0.z, ar0.w);
            w0[2] = cvtpk(ar1.x, ar1.y); w0[3] = cvtpk(ar1.z, ar1.w);
            w1[0] = cvtpk(ar2.x, ar2.y); w1[1] = cvtpk(ar2.z, ar2.w);
            w1[2] = cvtpk(ar3.x, ar3.y); w1[3] = cvtpk(ar3.z, ar3.w);
            asm volatile("" ::: "memory");
            // next-B first (stays in flight across the barrier below) ...
            if (k0 + 32 < K) stageB(k0 + 32, cur ^ 1);
            asm volatile("" ::: "memory");
            // ... then next A
            if (k0 + 32 < K) loadA(k0 + 32);
            asm volatile("" ::: "memory");
            *(u32x4*)&As[srow * 32 + skk]        = w0;
            *(u32x4*)&As[(64 + srow) * 32 + skk] = w1;
            if (k0 + 32 < K)
                asm volatile("s_waitcnt vmcnt(6) lgkmcnt(0)" ::: "memory");
            else
                asm volatile("s_waitcnt vmcnt(0) lgkmcnt(0)" ::: "memory");
            __builtin_amdgcn_s_barrier();
            asm volatile("" ::: "memory");
        } else {
            // barrier 1: previous iter's ds-reads of buf^1 are complete
            asm volatile("s_waitcnt lgkmcnt(0)" ::: "memory");
            __builtin_amdgcn_s_barrier();
            asm volatile("" ::: "memory");
            if (k0 + 32 < K) {
                stageT(k0 + 32, cur ^ 1);     // overwrite-safe after barrier
                asm volatile("" ::: "memory");
                // tile cur's 3 loads are oldest -> <=3 outstanding => landed
                if constexpr (BN == 64)
                    asm volatile("s_waitcnt vmcnt(3)" ::: "memory");
                else
                    asm volatile("s_waitcnt vmcnt(0)" ::: "memory");
            } else {
                asm volatile("s_waitcnt vmcnt(0)" ::: "memory");
            }
            __builtin_amdgcn_s_barrier();
            asm volatile("" ::: "memory");
        }

        const int ao = AF32 ? 0 : cur * (128 * 32);
        const int bo = cur * (BN * 32);
        bf16x8 a[4], b[NJ];
        #pragma unroll
        for (int i = 0; i < 4; ++i)
            a[i] = ldfrag(&As[ao + (wr + i * 16 + l15) * 32 + quad * 8]);
        #pragma unroll
        for (int j = 0; j < NJ; ++j)
            b[j] = ldfrag(&Bs[bo + (wc + j * 16 + l15) * 32 + quad * 8]);
        #pragma unroll
        for (int i = 0; i < 4; ++i)
            #pragma unroll
            for (int j = 0; j < NJ; ++j)
                acc[i][j] = __builtin_amdgcn_mfma_f32_16x16x32_bf16(
                    a[i], b[j], acc[i][j], 0, 0, 0);
        cur ^= 1;
    }

    #pragma unroll
    for (int j = 0; j < NJ; ++j) {
        const int col = n0 + wc + j * 16 + l15;
        const float bcol = bias[col];
        #pragma unroll
        for (int i = 0; i < 4; ++i) {
            const int row0 = m0 + wr + i * 16 + quad * 4;
            if (z == vt_z) {
                const int bb = row0 >> 11, s0 = row0 & 2047;
                const int4 mv = *(const int4*)&mask[bb * S_ + s0];
                u16x4 t;
                t[0] = mv.x ? f2bf((acc[i][j][0] + bcol) * scale) : (u16)0;
                t[1] = mv.y ? f2bf((acc[i][j][1] + bcol) * scale) : (u16)0;
                t[2] = mv.z ? f2bf((acc[i][j][2] + bcol) * scale) : (u16)0;
                t[3] = mv.w ? f2bf((acc[i][j][3] + bcol) * scale) : (u16)0;
                *(u16x4*)&((u16*)C)[((size_t)bb * E_ + col) * S_ + s0] = t;
            } else {
                #pragma unroll
                for (int r = 0; r < 4; ++r) {
                    const int row = row0 + r;
                    const float v = (acc[i][j][r] + bcol) * scale;
                    if (c_f32) ((float*)C)[(size_t)row * 1024 + col] = v;
                    else       ((u16*)C)[(size_t)row * 1024 + col]  = f2bf(v);
                }
            }
        }
    }
}

// ---------------------------------------------------------------------------
// Flash attention v15 (proven 63.8us): v12 + XCD-chunked block swizzle.
// ---------------------------------------------------------------------------
__global__ __launch_bounds__(512, 4)
void attn_v15(const u16* __restrict__ Q, const u16* __restrict__ K,
              const u16* __restrict__ Vt_g, const int* __restrict__ mask,
              u16* __restrict__ ctx)
{
    // per buffer 8192 u16: K 64x64 at [0], V(d-major) 64x64 at [4096]
    __shared__ alignas(16) u16 smem[2][8192];
    __shared__ alignas(16) u16 Mbf[S_];      // bf16 {0,1} mask table (4KB)
    __shared__ float scrl[256];

    const int tid  = threadIdx.x;
    const int lane = tid & 63;
    const int wv   = tid >> 6;          // 0..7
    const int l31  = lane & 31;
    const int half = lane >> 5;
    const int sw7  = lane & 7;
    const int qw   = wv & 3;            // q-strip (32 rows)
    const int kh   = wv >> 2;           // key-half of the 64-key chunk
    const int kbase = kh * 32;

    // XCD-chunked remap: XCD r -> bh in [4r, 4r+4), all 16 qt
    const int nwg = gridDim.x * gridDim.y;     // 512
    int wg = blockIdx.y * gridDim.x + blockIdx.x;
    wg = (wg & 7) * (nwg >> 3) + (wg >> 3);
    const int qt = wg % gridDim.x;             // gridDim.x = 16
    const int bh = wg / gridDim.x;
    const int b  = bh >> 4, h = bh & 15;

    const size_t qk_off = (size_t)b * S_ * E_ + (size_t)h * DH_;
    const size_t vt_off = ((size_t)b * E_ + (size_t)h * DH_) * S_;
    const int* mrow = &mask[b * S_];

    // one-time: mask -> bf16 multiplier table (visible after first barrier)
    {
        const int i = tid * 4;
        const int4 m = *(const int4*)&mrow[i];
        u16x4 t;
        t[0] = m.x ? (u16)0x3F80 : (u16)0;
        t[1] = m.y ? (u16)0x3F80 : (u16)0;
        t[2] = m.z ? (u16)0x3F80 : (u16)0;
        t[3] = m.w ? (u16)0x3F80 : (u16)0;
        *(u16x4*)&Mbf[i] = t;
    }

    // Q B-fragments (col = q = l31, k = d), loop-invariant
    const int q0 = qt * 128 + qw * 32;
    bf16x8 qf[4];
    #pragma unroll
    for (int s = 0; s < 4; ++s)
        qf[s] = ldfrag(&Q[qk_off + (size_t)(q0 + l31) * E_ + s * 16 + half * 8]);

    f32x16 O[2] = {};   // [d-tile]  rows = q-local, col = d = l31
    f32x16 lacc = {};   // l partial, same row mapping (col-broadcast)

    // staging: 1 K-gld16 + 1 V-gld16 per thread per chunk; XOR placement
    auto stage = [&](int kc, int buf) {
        const int rr = tid >> 3;              // key (K) / d-row (V), 0..63
        const int ks = tid & 7;               // LDS slot
        const int gb = ks ^ (rr & 7);         // global 8-elem block
        gld16(&K[qk_off + (size_t)(kc + rr) * E_ + gb * 8],
              &smem[buf][rr * 64 + ks * 8]);
        gld16(&Vt_g[vt_off + (size_t)rr * S_ + kc + gb * 8],
              &smem[buf][4096 + rr * 64 + ks * 8]);
    };

    stage(0, 0);
    int cur = 0;

    for (int kc = 0; kc < S_; kc += 64) {
        __syncthreads();                 // drains gld16s -> buf[cur] ready
        if (kc + 64 < S_) stage(kc + 64, cur ^ 1);
        const u16* Kb = &smem[cur][0];
        const u16* Vb = &smem[cur][4096];

        // St[key][q] for this wave-group's 32 keys
        __builtin_amdgcn_s_setprio(1);
        f32x16 St = {};
        #pragma unroll
        for (int s = 0; s < 4; ++s) {
            bf16x8 kf = ldfrag(&Kb[(kbase + l31) * 64 + ((s * 2 + half) ^ sw7) * 8]);
            St = __builtin_amdgcn_mfma_f32_32x32x16_bf16(kf, qf[s], St, 0, 0, 0);
        }
        __builtin_amdgcn_s_setprio(0);
        float ex[16];
        #pragma unroll
        for (int i = 0; i < 16; ++i) ex[i] = __builtin_exp2f(St[i]);

        // pack to bf16 (the values PV and l will consume)
        uint32_t wd[8];
        #pragma unroll
        for (int i = 0; i < 8; ++i) wd[i] = cvtpk(ex[2 * i], ex[2 * i + 1]);

        // permlane32_swap -> A-frags in natural key order
        u32x2v r02 = __builtin_amdgcn_permlane32_swap(wd[0], wd[2], false, false);
        u32x2v r13 = __builtin_amdgcn_permlane32_swap(wd[1], wd[3], false, false);
        u32x2v r46 = __builtin_amdgcn_permlane32_swap(wd[4], wd[6], false, false);
        u32x2v r57 = __builtin_amdgcn_permlane32_swap(wd[5], wd[7], false, false);
        u32x4 f0, f1;
        f0[0] = r02[0]; f0[1] = r13[0]; f0[2] = r02[1]; f0[3] = r13[1];
        f1[0] = r46[0]; f1[1] = r57[0]; f1[2] = r46[1]; f1[3] = r57[1];
        const bf16x8 pa0 = __builtin_bit_cast(bf16x8, f0);  // keys kbase+0..15
        const bf16x8 pa1 = __builtin_bit_cast(bf16x8, f1);  // keys kbase+16..31

        __builtin_amdgcn_s_setprio(1);
        // l += P @ maskvec (broadcast ds_reads; v8-proven semantics)
        {
            bf16x8 mb0 = ldfrag(&Mbf[kc + kbase + half * 8]);
            bf16x8 mb1 = ldfrag(&Mbf[kc + kbase + 16 + half * 8]);
            lacc = __builtin_amdgcn_mfma_f32_32x32x16_bf16(pa0, mb0, lacc, 0, 0, 0);
            lacc = __builtin_amdgcn_mfma_f32_32x32x16_bf16(pa1, mb1, lacc, 0, 0, 0);
        }

        // O += P @ V   (masked V cols are zero)
        #pragma unroll
        for (int nt = 0; nt < 2; ++nt) {
            const int drow = nt * 32 + l31;
            const int kb0 = kh * 4 + half;
            const int kb1 = kh * 4 + 2 + half;
            bf16x8 vb0 = ldfrag(&Vb[drow * 64 + (kb0 ^ sw7) * 8]);
            bf16x8 vb1 = ldfrag(&Vb[drow * 64 + (kb1 ^ sw7) * 8]);
            O[nt] = __builtin_amdgcn_mfma_f32_32x32x16_bf16(pa0, vb0, O[nt], 0, 0, 0);
            O[nt] = __builtin_amdgcn_mfma_f32_32x32x16_bf16(pa1, vb1, O[nt], 0, 0, 0);
        }
        __builtin_amdgcn_s_setprio(0);
        cur ^= 1;
    }

    // combine key-halves; O scratch overlays smem (8192 f32, XOR-slotted);
    // l goes through scrl (lacc is col-broadcast -> one lane per (wv,half)).
    __syncthreads();
    float* scr = (float*)smem;
    const int sbase = (qw * 64 + lane) * 32;
    if (kh == 1) {
        #pragma unroll
        for (int j = 0; j < 4; ++j) {
            f32x4 t0, t1;
            #pragma unroll
            for (int r = 0; r < 4; ++r) { t0[r] = O[0][j * 4 + r]; t1[r] = O[1][j * 4 + r]; }
            *(f32x4*)&scr[sbase + (j ^ sw7) * 4]       = t0;
            *(f32x4*)&scr[sbase + ((j + 4) ^ sw7) * 4] = t1;
        }
        if (l31 == 0) {
            #pragma unroll
            for (int i = 0; i < 16; ++i)
                scrl[qw * 32 + half * 16 + i] = lacc[i];
        }
    }
    __syncthreads();
    if (kh == 0) {
        #pragma unroll
        for (int nt = 0; nt < 2; ++nt) {
            #pragma unroll
            for (int j = 0; j < 4; ++j) {
                const f32x4 p = *(const f32x4*)&scr[sbase + (((nt * 4 + j) ^ sw7)) * 4];
                #pragma unroll
                for (int r = 0; r < 4; ++r) {
                    const int i  = j * 4 + r;
                    const int ql = (i & 3) + 8 * (i >> 2) + 4 * half;
                    const float lt = lacc[i] + scrl[qw * 32 + half * 16 + i];
                    const float o  = O[nt][i] + p[r];
                    const int q = q0 + ql;
                    const int e = h * DH_ + nt * 32 + l31;
                    ctx[((size_t)b * S_ + q) * E_ + e] = f2bf(o / lt);
                }
            }
        }
    }
}

// ---------------------------------------------------------------------------
// Fallback tier kernels (r6/r7, proven, unchanged)
// ---------------------------------------------------------------------------
__global__ __launch_bounds__(256)
void gemm_bias(const void* __restrict__ A, int a_f32,
               const float* __restrict__ W, const float* __restrict__ bias,
               void* __restrict__ C, int c_f32,
               int M, int N, int K, float scale)
{
    __shared__ alignas(16) u16 As[64 * 32];
    __shared__ alignas(16) u16 Wt[64 * 32];
    const int tid  = threadIdx.x;
    const int lane = tid & 63;
    const int wv   = tid >> 6;
    const int l15  = lane & 15;
    const int quad = lane >> 4;
    const int m0 = blockIdx.y * 64, n0 = blockIdx.x * 64;
    const int wr = (wv >> 1) * 32, wc = (wv & 1) * 32;
    const int ar = tid >> 2, ac = (tid & 3) * 8;
    const int wk = tid >> 3, wn = (tid & 7) * 8;
    f32x4 acc[2][2] = {};
    for (int k0 = 0; k0 < K; k0 += 32) {
        __syncthreads();
        if (a_f32) {
            const float* Af = (const float*)A;
            const float* p = &Af[(size_t)(m0 + ar) * K + k0 + ac];
            float4 f0 = *(const float4*)p; float4 f1 = *(const float4*)(p + 4);
            u16x8 t;
            t[0] = f2bf(f0.x); t[1] = f2bf(f0.y); t[2] = f2bf(f0.z); t[3] = f2bf(f0.w);
            t[4] = f2bf(f1.x); t[5] = f2bf(f1.y); t[6] = f2bf(f1.z); t[7] = f2bf(f1.w);
            *(u16x8*)&As[ar * 32 + ac] = t;
        } else {
            const u16* Ab = (const u16*)A;
            *(u16x8*)&As[ar * 32 + ac] = *(const u16x8*)&Ab[(size_t)(m0 + ar) * K + k0 + ac];
        }
        {
            const float* p = &W[(size_t)(k0 + wk) * N + n0 + wn];
            float4 g0 = *(const float4*)p; float4 g1 = *(const float4*)(p + 4);
            float fv[8] = {g0.x, g0.y, g0.z, g0.w, g1.x, g1.y, g1.z, g1.w};
            #pragma unroll
            for (int j = 0; j < 8; ++j) Wt[(wn + j) * 32 + wk] = f2bf(fv[j]);
        }
        __syncthreads();
        bf16x8 a[2], b[2];
        #pragma unroll
        for (int sm = 0; sm < 2; ++sm) a[sm] = ldfrag(&As[(wr + sm * 16 + l15) * 32 + quad * 8]);
        #pragma unroll
        for (int sn = 0; sn < 2; ++sn) b[sn] = ldfrag(&Wt[(wc + sn * 16 + l15) * 32 + quad * 8]);
        #pragma unroll
        for (int sm = 0; sm < 2; ++sm)
            #pragma unroll
            for (int sn = 0; sn < 2; ++sn)
                acc[sm][sn] = __builtin_amdgcn_mfma_f32_16x16x32_bf16(a[sm], b[sn], acc[sm][sn], 0, 0, 0);
    }
    #pragma unroll
    for (int sm = 0; sm < 2; ++sm)
        #pragma unroll
        for (int sn = 0; sn < 2; ++sn) {
            const int col = n0 + wc + sn * 16 + l15;
            const float bcol = bias[col];
            #pragma unroll
            for (int r = 0; r < 4; ++r) {
                const int row = m0 + wr + sm * 16 + quad * 4 + r;
                const float v = (acc[sm][sn][r] + bcol) * scale;
                if (c_f32) ((float*)C)[(size_t)row * N + col] = v;
                else       ((u16*)C)[(size_t)row * N + col]  = f2bf(v);
            }
        }
}

__global__ __launch_bounds__(256)
void attn_v2(const u16* __restrict__ Q, const u16* __restrict__ K,
             const u16* __restrict__ V, const int* __restrict__ mask,
             u16* __restrict__ ctx, int BH_per_B)
{
    __shared__ alignas(16) u16 Ks[64 * 72];
    __shared__ alignas(16) u16 Vt[64 * 72];
    __shared__ alignas(16) u16 Pb[4][16 * 72];
    const int tid  = threadIdx.x;
    const int lane = tid & 63;
    const int wv   = tid >> 6;
    const int l15  = lane & 15;
    const int quad = lane >> 4;
    const int qt = blockIdx.x;
    const int bh = blockIdx.y;
    const int b  = bh / BH_per_B, h = bh % BH_per_B;
    const size_t headoff = (size_t)b * S_ * E_ + (size_t)h * DH_;
    const int qrow = qt * 64 + wv * 16 + l15;
    const bf16x8 qf0 = ldfrag(&Q[headoff + (size_t)qrow * E_ + quad * 8]);
    const bf16x8 qf1 = ldfrag(&Q[headoff + (size_t)qrow * E_ + 32 + quad * 8]);
    f32x4 oacc[4] = {};
    float mrun[4] = {-1e30f, -1e30f, -1e30f, -1e30f};
    float lrun[4] = {0.f, 0.f, 0.f, 0.f};
    const int skey = tid >> 2;
    const int sd0  = (tid & 3) * 16;
    for (int kc = 0; kc < S_; kc += 64) {
        __syncthreads();
        {
            const u16* kg = &K[headoff + (size_t)(kc + skey) * E_ + sd0];
            *(u16x8*)&Ks[skey * 72 + sd0]     = *(const u16x8*)kg;
            *(u16x8*)&Ks[skey * 72 + sd0 + 8] = *(const u16x8*)(kg + 8);
            const u16* vg = &V[headoff + (size_t)(kc + skey) * E_ + sd0];
            u16x8 v0 = *(const u16x8*)vg;
            u16x8 v1 = *(const u16x8*)(vg + 8);
            #pragma unroll
            for (int j = 0; j < 8; ++j) {
                const int d = sd0 + j;
                Vt[d * 72 + (skey ^ (((d >> 3) & 7) * 8))] = v0[j];
            }
            #pragma unroll
            for (int j = 0; j < 8; ++j) {
                const int d = sd0 + 8 + j;
                Vt[d * 72 + (skey ^ (((d >> 3) & 7) * 8))] = v1[j];
            }
        }
        __syncthreads();
        f32x4 sb[4];
        #pragma unroll
        for (int t = 0; t < 4; ++t) {
            bf16x8 kf0 = ldfrag(&Ks[(t * 16 + l15) * 72 + quad * 8]);
            bf16x8 kf1 = ldfrag(&Ks[(t * 16 + l15) * 72 + 32 + quad * 8]);
            f32x4 s = {};
            s = __builtin_amdgcn_mfma_f32_16x16x32_bf16(qf0, kf0, s, 0, 0, 0);
            s = __builtin_amdgcn_mfma_f32_16x16x32_bf16(qf1, kf1, s, 0, 0, 0);
            const int mv = mask[b * S_ + kc + t * 16 + l15];
            #pragma unroll
            for (int r = 0; r < 4; ++r) sb[t][r] = (mv == 0) ? -1e9f : s[r];
        }
        #pragma unroll
        for (int r = 0; r < 4; ++r) {
            float m = fmaxf(fmaxf(sb[0][r], sb[1][r]), fmaxf(sb[2][r], sb[3][r]));
            #pragma unroll
            for (int off = 1; off < 16; off <<= 1) m = fmaxf(m, __shfl_xor(m, off));
            const float mnew  = fmaxf(mrun[r], m);
            const float alpha = __expf(mrun[r] - mnew);
            mrun[r] = mnew;
            float sum = 0.f;
            #pragma unroll
            for (int t = 0; t < 4; ++t) {
                const float p = __expf(sb[t][r] - mnew);
                sb[t][r] = p; sum += p;
            }
            #pragma unroll
            for (int off = 1; off < 16; off <<= 1) sum += __shfl_xor(sum, off);
            lrun[r] = lrun[r] * alpha + sum;
            #pragma unroll
            for (int c = 0; c < 4; ++c) oacc[c][r] *= alpha;
        }
        #pragma unroll
        for (int t = 0; t < 4; ++t)
            #pragma unroll
            for (int r = 0; r < 4; ++r)
                Pb[wv][(quad * 4 + r) * 72 + t * 16 + l15] = f2bf(sb[t][r]);
        const bf16x8 pa0 = ldfrag(&Pb[wv][l15 * 72 + quad * 8]);
        const bf16x8 pa1 = ldfrag(&Pb[wv][l15 * 72 + 32 + quad * 8]);
        #pragma unroll
        for (int c = 0; c < 4; ++c) {
            const int d = c * 16 + l15;
            const int sg = ((d >> 3) & 7) * 8;
            bf16x8 vb0 = ldfrag(&Vt[d * 72 + ((quad * 8) ^ sg)]);
            bf16x8 vb1 = ldfrag(&Vt[d * 72 + ((32 + quad * 8) ^ sg)]);
            oacc[c] = __builtin_amdgcn_mfma_f32_16x16x32_bf16(pa0, vb0, oacc[c], 0, 0, 0);
            oacc[c] = __builtin_amdgcn_mfma_f32_16x16x32_bf16(pa1, vb1, oacc[c], 0, 0, 0);
        }
    }
    #pragma unroll
    for (int c = 0; c < 4; ++c) {
        const int e = h * DH_ + c * 16 + l15;
        #pragma unroll
        for (int r = 0; r < 4; ++r) {
            const int qg = qt * 64 + wv * 16 + quad * 4 + r;
            ctx[((size_t)b * S_ + qg) * E_ + e] = f2bf(oacc[c][r] / lrun[r]);
        }
    }
}

// ---------------------------------------------------------------------------
extern "C" void kernel_launch(void* const* d_in, const int* in_sizes, int n_in,
                              void* d_out, int out_size, void* d_ws, size_t ws_size,
                              hipStream_t stream)
{
    const float* query = (const float*)d_in[0];
    const float* key   = (const float*)d_in[1];
    const float* value = (const float*)d_in[2];
    const int*   mask  = (const int*)d_in[3];
    const float* Wq = (const float*)d_in[4];  const float* bq = (const float*)d_in[5];
    const float* Wk = (const float*)d_in[6];  const float* bk = (const float*)d_in[7];
    const float* Wv = (const float*)d_in[8];  const float* bv = (const float*)d_in[9];
    const float* Wo = (const float*)d_in[10]; const float* bo = (const float*)d_in[11];
    float* out = (float*)d_out;

    u16* ws = (u16*)d_ws;
    dim3 blk(256);

    const size_t need_fancy = (size_t)(6 * MELEMS + 4 * WE) * sizeof(u16);  // 58.7 MB
    const size_t need_full  = (size_t)(4 * MELEMS) * sizeof(u16) + 64;      // 33.6 MB

    if (ws_size >= need_fancy) {
        u16* Qi  = ws;                 // Cp alias (staging region unused now)
        u16* Wqt = ws + 3 * (size_t)MELEMS;
        u16* Wkt = Wqt + WE;
        u16* Wvt = Wkt + WE;
        u16* Wot = Wvt + WE;
        u16* Qp  = Wot + WE;
        u16* Kp  = Qp + MELEMS;
        u16* Vp  = Kp + MELEMS;   // holds V^T [B][E][S], masked cols zeroed
        u16* Cp  = Qi;

        cvt_w<<<dim3(1024), blk, 0, stream>>>(Wq, Wk, Wv, Wo,
                                              Wqt, Wkt, Wvt, Wot);

        // Q scale folds softmax's 1/sqrt(DH) AND log2(e) (attn uses exp2).
        // A operands are RAW fp32 inputs; conversion fused into staging
        // with counted-vmcnt barriers + double-buffered B (v22).
        gemm_bt<128, 1><<<dim3(8, 32, 3), blk, 0, stream>>>(
            query, key, value, Wqt, Wkt, Wvt, bq, bk, bv,
            Qp, Kp, Vp, mask, 0, /*vt_z=*/2, 0.125f * 1.44269504f, E_);

        attn_v15<<<dim3(S_ / 128, B_ * H_), dim3(512), 0, stream>>>(
            Qp, Kp, Vp, mask, Cp);

        // output GEMM: BN=64 (512 blocks, 2/CU) + v21 dbuf counted-vmcnt
        gemm_bt<64, 0><<<dim3(16, 32, 1), blk, 0, stream>>>(
            Cp, Cp, Cp, Wot, Wot, Wot, bo, bo, bo,
            out, out, out, mask, 1, /*vt_z=*/-1, 1.0f, E_);
    } else if (ws_size >= need_full) {
        u16* Qp = ws;
        u16* Kp = ws + MELEMS;
        u16* Vp = ws + 2 * MELEMS;
        u16* Cp = ws + 3 * MELEMS;
        const int M = B_ * S_;
        dim3 gg(E_ / 64, M / 64);
        gemm_bias<<<gg, blk, 0, stream>>>(query, 1, Wq, bq, Qp, 0, M, E_, E_, 0.125f);
        gemm_bias<<<gg, blk, 0, stream>>>(key,   1, Wk, bk, Kp, 0, M, E_, E_, 1.0f);
        gemm_bias<<<gg, blk, 0, stream>>>(value, 1, Wv, bv, Vp, 0, M, E_, E_, 1.0f);
        attn_v2<<<dim3(S_ / 64, B_ * H_), blk, 0, stream>>>(Qp, Kp, Vp, mask, Cp, H_);
        gemm_bias<<<gg, blk, 0, stream>>>(Cp, 0, Wo, bo, out, 1, M, E_, E_, 1.0f);
    } else {
        const size_t szb = (size_t)S_ * E_;
        u16* Qp = ws; u16* Kp = ws + szb; u16* Vp = ws + 2 * szb; u16* Cp = ws + 3 * szb;
        dim3 gg(E_ / 64, S_ / 64);
        for (int b = 0; b < B_; ++b) {
            gemm_bias<<<gg, blk, 0, stream>>>(query + b * szb, 1, Wq, bq, Qp, 0, S_, E_, E_, 0.125f);
            gemm_bias<<<gg, blk, 0, stream>>>(key   + b * szb, 1, Wk, bk, Kp, 0, S_, E_, E_, 1.0f);
            gemm_bias<<<gg, blk, 0, stream>>>(value + b * szb, 1, Wv, bv, Vp, 0, S_, E_, E_, 1.0f);
            attn_v2<<<dim3(S_ / 64, H_), blk, 0, stream>>>(Qp, Kp, Vp, mask + b * S_, Cp, H_);
            gemm_bias<<<gg, blk, 0, stream>>>(Cp, 0, Wo, bo, ((float*)d_out) + b * szb, 1, S_, E_, E_, 1.0f);
        }
    }
}

// Round 25
// 131.990 us; speedup vs baseline: 1.0006x; 1.0006x over previous
//
#include <hip/hip_runtime.h>
#include <hip/hip_bf16.h>
#include <stdint.h>

#define B_ 2
#define S_ 2048
#define E_ 1024
#define H_ 16
#define DH_ 64
#define MELEMS (4096 * 1024)   // B*S*E
#define WE (1024 * 1024)

typedef unsigned short u16;
typedef __bf16 bf16x8 __attribute__((ext_vector_type(8)));
typedef u16 u16x8 __attribute__((ext_vector_type(8)));
typedef u16 u16x4 __attribute__((ext_vector_type(4)));
typedef float f32x4 __attribute__((ext_vector_type(4)));
typedef float f32x16 __attribute__((ext_vector_type(16)));
typedef uint32_t u32x4 __attribute__((ext_vector_type(4)));
typedef uint32_t u32x2v __attribute__((ext_vector_type(2)));

__device__ __forceinline__ float bf2f(u16 u) {
    union { uint32_t i; float f; } v; v.i = ((uint32_t)u) << 16; return v.f;
}
__device__ __forceinline__ u16 f2bf(float f) {   // RNE fp32->bf16
    union { float f; uint32_t i; } v; v.f = f;
    uint32_t r = (v.i + 0x7FFFu + ((v.i >> 16) & 1u)) >> 16;
    return (u16)r;
}
// single-instruction packed f32x2 -> bf16x2 (RNE, same results as f2bf)
__device__ __forceinline__ uint32_t cvtpk(float a, float b) {
    uint32_t r;
    asm("v_cvt_pk_bf16_f32 %0, %1, %2" : "=v"(r) : "v"(a), "v"(b));
    return r;
}
__device__ __forceinline__ bf16x8 ldfrag(const u16* p) {
    u16x8 t = *(const u16x8*)p;
    return __builtin_bit_cast(bf16x8, t);
}
__device__ __forceinline__ void gld16(const void* g, void* l) {
    __builtin_amdgcn_global_load_lds(
        (const __attribute__((address_space(1))) void*)g,
        (__attribute__((address_space(3))) void*)l, 16, 0, 0);
}

// ---------------------------------------------------------------------------
// Weight transpose only: W[K][N] fp32 -> Wt[N][K] bf16 (LDS-tiled, 65-stride).
// ---------------------------------------------------------------------------
__global__ __launch_bounds__(256)
void cvt_w(const float* __restrict__ W0, const float* __restrict__ W1,
           const float* __restrict__ W2, const float* __restrict__ W3,
           u16* __restrict__ T0, u16* __restrict__ T1,
           u16* __restrict__ T2, u16* __restrict__ T3)
{
    __shared__ float tile[64][65];
    const int rr = blockIdx.x;          // 0..1023
    const int tid = threadIdx.x;
    const int z = rr >> 8;
    const int tt = rr & 255;
    const float* W = (z == 0) ? W0 : (z == 1) ? W1 : (z == 2) ? W2 : W3;
    u16* T = (z == 0) ? T0 : (z == 1) ? T1 : (z == 2) ? T2 : T3;
    const int n0 = (tt & 15) * 64, k0 = (tt >> 4) * 64;
    const int r = tid >> 2, c0 = (tid & 3) * 16;

    #pragma unroll
    for (int i = 0; i < 4; ++i) {
        float4 w = *(const float4*)&W[(size_t)(k0 + r) * 1024 + n0 + c0 + i * 4];
        tile[r][c0 + i * 4 + 0] = w.x; tile[r][c0 + i * 4 + 1] = w.y;
        tile[r][c0 + i * 4 + 2] = w.z; tile[r][c0 + i * 4 + 3] = w.w;
    }
    __syncthreads();
    u16x8 a, b;
    #pragma unroll
    for (int j = 0; j < 8; ++j) a[j] = f2bf(tile[c0 + j][r]);
    #pragma unroll
    for (int j = 0; j < 8; ++j) b[j] = f2bf(tile[c0 + 8 + j][r]);
    *(u16x8*)&T[(size_t)(n0 + r) * 1024 + k0 + c0] = a;
    *(u16x8*)&T[(size_t)(n0 + r) * 1024 + k0 + c0 + 8] = b;
}

// ---------------------------------------------------------------------------
// m97-style GEMM: C = (A[M,K] @ Bt[N,K]^T + bias[N]) * scale.
// AF32=1 (v22-proven): A fp32 fused conversion + DOUBLE-BUFFERED B, counted
//   vmcnt: per iter: lgkmcnt(0)+barrier -> cvtpk A (compiler's A-reg wait
//   drains the OLDER current-B gld16s: B always issued before A) -> issue
//   B(k+32)->Bs[cur^1] -> loadA(k+32) -> ds_write As -> vmcnt(6)+lgkmcnt(0)
//   (6 newest = next-B 2 + next-A 4 in flight; current B older -> landed)
//   -> barrier -> 16 MFMAs.  B-latency cover: full iteration (~800 cyc).
// AF32=0 (v21-proven): double-buffered counted-vmcnt tile staging.
// z==vt_z: writes V^T [B][E][S] with masked key COLUMNS zeroed.
// XCD-chunked block swizzle (T1).
// ---------------------------------------------------------------------------
template<int BN, int AF32>
__global__ __launch_bounds__(256)
void gemm_bt(const void* __restrict__ A0, const void* __restrict__ A1,
             const void* __restrict__ A2,
             const u16* __restrict__ Bt0, const u16* __restrict__ Bt1,
             const u16* __restrict__ Bt2,
             const float* __restrict__ b0, const float* __restrict__ b1,
             const float* __restrict__ b2,
             void* __restrict__ C0, void* __restrict__ C1, void* __restrict__ C2,
             const int* __restrict__ mask,
             int c_f32, int vt_z, float scale0, int K)
{
    const int z = blockIdx.z;
    const void* Av = (z == 0) ? A0 : (z == 1) ? A1 : A2;
    const u16* Bt = (z == 0) ? Bt0 : (z == 1) ? Bt1 : Bt2;
    const float* bias = (z == 0) ? b0 : (z == 1) ? b1 : b2;
    void* C = (z == 0) ? C0 : (z == 1) ? C1 : C2;
    const float scale = (z == 0) ? scale0 : 1.0f;

    // AF32=1: A single-buffered (arrives via regs), B double.  AF32=0: both double.
    __shared__ alignas(16) u16 As[(AF32 ? 1 : 2) * 128 * 32];
    __shared__ alignas(16) u16 Bs[2 * BN * 32];

    const int tid  = threadIdx.x;
    const int lane = tid & 63;
    const int wv   = tid >> 6;
    const int l15  = lane & 15;
    const int quad = lane >> 4;

    // XCD-chunked remap within this z-slice
    const int nwg = gridDim.x * gridDim.y;
    int wg = blockIdx.y * gridDim.x + blockIdx.x;
    wg = (wg & 7) * (nwg >> 3) + (wg >> 3);
    const int bx = wg % gridDim.x;
    const int by = wg / gridDim.x;

    const int m0 = by * 128;
    const int n0 = bx * BN;
    const int wr = (wv >> 1) * 64;
    const int wc = (wv & 1) * (BN / 2);

    const int srow = wv * 16 + (lane >> 2);
    const int skk  = (lane & 3) * 8;

    constexpr int NJ = BN / 32;
    f32x4 acc[4][NJ] = {};

    float4 ar0, ar1, ar2, ar3;      // AF32 staging regs (2 rows x 32B)
    auto loadA = [&](int k0) {
        const float* Af = (const float*)Av;
        const float* p0 = &Af[(size_t)(m0 + srow) * K + k0 + skk];
        const float* p1 = &Af[(size_t)(m0 + 64 + srow) * K + k0 + skk];
        ar0 = *(const float4*)p0;  ar1 = *(const float4*)(p0 + 4);
        ar2 = *(const float4*)p1;  ar3 = *(const float4*)(p1 + 4);
    };
    // stage B tile into buffer `buf` (BN/64 gld16 per thread)
    auto stageB = [&](int k0, int buf) {
        const int bo = buf * (BN * 32);
        #pragma unroll
        for (int h = 0; h < BN / 64; ++h) {
            const int r = h * 64 + srow;
            gld16(&Bt[(size_t)(n0 + r) * K + k0 + skk], &Bs[bo + r * 32 + skk]);
        }
    };
    // AF32=0: stage one full tile (A 2x + B) into buffer `buf`
    auto stageT = [&](int k0, int buf) {
        const u16* Ab = (const u16*)Av;
        const int ao = buf * (128 * 32);
        #pragma unroll
        for (int h = 0; h < 2; ++h) {
            const int r = h * 64 + srow;
            gld16(&Ab[(size_t)(m0 + r) * K + k0 + skk], &As[ao + r * 32 + skk]);
        }
        stageB(k0, buf);
    };

    if (AF32) {
        stageB(0, 0);                 // B first (oldest in FIFO)
        asm volatile("" ::: "memory");
        loadA(0);
        asm volatile("" ::: "memory");
    } else {
        stageT(0, 0);
        asm volatile("" ::: "memory");
    }

    int cur = 0;
    for (int k0 = 0; k0 < K; k0 += 32) {
        if (AF32) {
            // top barrier: ds-reads done; in-flight loads survive
            asm volatile("s_waitcnt lgkmcnt(0)" ::: "memory");
            __builtin_amdgcn_s_barrier();
            asm volatile("" ::: "memory");
            // pack current A; compiler's wait for the A regs also drains the
            // OLDER current-B gld16s (B always issued before A) -> Bs[cur] ok
            u32x4 w0, w1;
            w0[0] = cvtpk(ar0.x, ar0.y); w0[1] = cvtpk(ar0.z, ar0.w);
            w0[2] = cvtpk(ar1.x, ar1.y); w0[3] = cvtpk(ar1.z, ar1.w);
            w1[0] = cvtpk(ar2.x, ar2.y); w1[1] = cvtpk(ar2.z, ar2.w);
            w1[2] = cvtpk(ar3.x, ar3.y); w1[3] = cvtpk(ar3.z, ar3.w);
            asm volatile("" ::: "memory");
            // next-B first (stays in flight across the barrier below) ...
            if (k0 + 32 < K) stageB(k0 + 32, cur ^ 1);
            asm volatile("" ::: "memory");
            // ... then next A
            if (k0 + 32 < K) loadA(k0 + 32);
            asm volatile("" ::: "memory");
            *(u32x4*)&As[srow * 32 + skk]        = w0;
            *(u32x4*)&As[(64 + srow) * 32 + skk] = w1;
            if (k0 + 32 < K)
                asm volatile("s_waitcnt vmcnt(6) lgkmcnt(0)" ::: "memory");
            else
                asm volatile("s_waitcnt vmcnt(0) lgkmcnt(0)" ::: "memory");
            __builtin_amdgcn_s_barrier();
            asm volatile("" ::: "memory");
        } else {
            // barrier 1: previous iter's ds-reads of buf^1 are complete
            asm volatile("s_waitcnt lgkmcnt(0)" ::: "memory");
            __builtin_amdgcn_s_barrier();
            asm volatile("" ::: "memory");
            if (k0 + 32 < K) {
                stageT(k0 + 32, cur ^ 1);     // overwrite-safe after barrier
                asm volatile("" ::: "memory");
                // tile cur's 3 loads are oldest -> <=3 outstanding => landed
                if constexpr (BN == 64)
                    asm volatile("s_waitcnt vmcnt(3)" ::: "memory");
                else
                    asm volatile("s_waitcnt vmcnt(0)" ::: "memory");
            } else {
                asm volatile("s_waitcnt vmcnt(0)" ::: "memory");
            }
            __builtin_amdgcn_s_barrier();
            asm volatile("" ::: "memory");
        }

        const int ao = AF32 ? 0 : cur * (128 * 32);
        const int bo = cur * (BN * 32);
        bf16x8 a[4], b[NJ];
        #pragma unroll
        for (int i = 0; i < 4; ++i)
            a[i] = ldfrag(&As[ao + (wr + i * 16 + l15) * 32 + quad * 8]);
        #pragma unroll
        for (int j = 0; j < NJ; ++j)
            b[j] = ldfrag(&Bs[bo + (wc + j * 16 + l15) * 32 + quad * 8]);
        #pragma unroll
        for (int i = 0; i < 4; ++i)
            #pragma unroll
            for (int j = 0; j < NJ; ++j)
                acc[i][j] = __builtin_amdgcn_mfma_f32_16x16x32_bf16(
                    a[i], b[j], acc[i][j], 0, 0, 0);
        cur ^= 1;
    }

    #pragma unroll
    for (int j = 0; j < NJ; ++j) {
        const int col = n0 + wc + j * 16 + l15;
        const float bcol = bias[col];
        #pragma unroll
        for (int i = 0; i < 4; ++i) {
            const int row0 = m0 + wr + i * 16 + quad * 4;
            if (z == vt_z) {
                const int bb = row0 >> 11, s0 = row0 & 2047;
                const int4 mv = *(const int4*)&mask[bb * S_ + s0];
                u16x4 t;
                t[0] = mv.x ? f2bf((acc[i][j][0] + bcol) * scale) : (u16)0;
                t[1] = mv.y ? f2bf((acc[i][j][1] + bcol) * scale) : (u16)0;
                t[2] = mv.z ? f2bf((acc[i][j][2] + bcol) * scale) : (u16)0;
                t[3] = mv.w ? f2bf((acc[i][j][3] + bcol) * scale) : (u16)0;
                *(u16x4*)&((u16*)C)[((size_t)bb * E_ + col) * S_ + s0] = t;
            } else {
                #pragma unroll
                for (int r = 0; r < 4; ++r) {
                    const int row = row0 + r;
                    const float v = (acc[i][j][r] + bcol) * scale;
                    if (c_f32) ((float*)C)[(size_t)row * 1024 + col] = v;
                    else       ((u16*)C)[(size_t)row * 1024 + col]  = f2bf(v);
                }
            }
        }
    }
}

// ---------------------------------------------------------------------------
// Flash attention v15 (proven 63.8us): v12 + XCD-chunked block swizzle.
// ---------------------------------------------------------------------------
__global__ __launch_bounds__(512, 4)
void attn_v15(const u16* __restrict__ Q, const u16* __restrict__ K,
              const u16* __restrict__ Vt_g, const int* __restrict__ mask,
              u16* __restrict__ ctx)
{
    // per buffer 8192 u16: K 64x64 at [0], V(d-major) 64x64 at [4096]
    __shared__ alignas(16) u16 smem[2][8192];
    __shared__ alignas(16) u16 Mbf[S_];      // bf16 {0,1} mask table (4KB)
    __shared__ float scrl[256];

    const int tid  = threadIdx.x;
    const int lane = tid & 63;
    const int wv   = tid >> 6;          // 0..7
    const int l31  = lane & 31;
    const int half = lane >> 5;
    const int sw7  = lane & 7;
    const int qw   = wv & 3;            // q-strip (32 rows)
    const int kh   = wv >> 2;           // key-half of the 64-key chunk
    const int kbase = kh * 32;

    // XCD-chunked remap: XCD r -> bh in [4r, 4r+4), all 16 qt
    const int nwg = gridDim.x * gridDim.y;     // 512
    int wg = blockIdx.y * gridDim.x + blockIdx.x;
    wg = (wg & 7) * (nwg >> 3) + (wg >> 3);
    const int qt = wg % gridDim.x;             // gridDim.x = 16
    const int bh = wg / gridDim.x;
    const int b  = bh >> 4, h = bh & 15;

    const size_t qk_off = (size_t)b * S_ * E_ + (size_t)h * DH_;
    const size_t vt_off = ((size_t)b * E_ + (size_t)h * DH_) * S_;
    const int* mrow = &mask[b * S_];

    // one-time: mask -> bf16 multiplier table (visible after first barrier)
    {
        const int i = tid * 4;
        const int4 m = *(const int4*)&mrow[i];
        u16x4 t;
        t[0] = m.x ? (u16)0x3F80 : (u16)0;
        t[1] = m.y ? (u16)0x3F80 : (u16)0;
        t[2] = m.z ? (u16)0x3F80 : (u16)0;
        t[3] = m.w ? (u16)0x3F80 : (u16)0;
        *(u16x4*)&Mbf[i] = t;
    }

    // Q B-fragments (col = q = l31, k = d), loop-invariant
    const int q0 = qt * 128 + qw * 32;
    bf16x8 qf[4];
    #pragma unroll
    for (int s = 0; s < 4; ++s)
        qf[s] = ldfrag(&Q[qk_off + (size_t)(q0 + l31) * E_ + s * 16 + half * 8]);

    f32x16 O[2] = {};   // [d-tile]  rows = q-local, col = d = l31
    f32x16 lacc = {};   // l partial, same row mapping (col-broadcast)

    // staging: 1 K-gld16 + 1 V-gld16 per thread per chunk; XOR placement
    auto stage = [&](int kc, int buf) {
        const int rr = tid >> 3;              // key (K) / d-row (V), 0..63
        const int ks = tid & 7;               // LDS slot
        const int gb = ks ^ (rr & 7);         // global 8-elem block
        gld16(&K[qk_off + (size_t)(kc + rr) * E_ + gb * 8],
              &smem[buf][rr * 64 + ks * 8]);
        gld16(&Vt_g[vt_off + (size_t)rr * S_ + kc + gb * 8],
              &smem[buf][4096 + rr * 64 + ks * 8]);
    };

    stage(0, 0);
    int cur = 0;

    for (int kc = 0; kc < S_; kc += 64) {
        __syncthreads();                 // drains gld16s -> buf[cur] ready
        if (kc + 64 < S_) stage(kc + 64, cur ^ 1);
        const u16* Kb = &smem[cur][0];
        const u16* Vb = &smem[cur][4096];

        // St[key][q] for this wave-group's 32 keys
        __builtin_amdgcn_s_setprio(1);
        f32x16 St = {};
        #pragma unroll
        for (int s = 0; s < 4; ++s) {
            bf16x8 kf = ldfrag(&Kb[(kbase + l31) * 64 + ((s * 2 + half) ^ sw7) * 8]);
            St = __builtin_amdgcn_mfma_f32_32x32x16_bf16(kf, qf[s], St, 0, 0, 0);
        }
        __builtin_amdgcn_s_setprio(0);
        float ex[16];
        #pragma unroll
        for (int i = 0; i < 16; ++i) ex[i] = __builtin_exp2f(St[i]);

        // pack to bf16 (the values PV and l will consume)
        uint32_t wd[8];
        #pragma unroll
        for (int i = 0; i < 8; ++i) wd[i] = cvtpk(ex[2 * i], ex[2 * i + 1]);

        // permlane32_swap -> A-frags in natural key order
        u32x2v r02 = __builtin_amdgcn_permlane32_swap(wd[0], wd[2], false, false);
        u32x2v r13 = __builtin_amdgcn_permlane32_swap(wd[1], wd[3], false, false);
        u32x2v r46 = __builtin_amdgcn_permlane32_swap(wd[4], wd[6], false, false);
        u32x2v r57 = __builtin_amdgcn_permlane32_swap(wd[5], wd[7], false, false);
        u32x4 f0, f1;
        f0[0] = r02[0]; f0[1] = r13[0]; f0[2] = r02[1]; f0[3] = r13[1];
        f1[0] = r46[0]; f1[1] = r57[0]; f1[2] = r46[1]; f1[3] = r57[1];
        const bf16x8 pa0 = __builtin_bit_cast(bf16x8, f0);  // keys kbase+0..15
        const bf16x8 pa1 = __builtin_bit_cast(bf16x8, f1);  // keys kbase+16..31

        __builtin_amdgcn_s_setprio(1);
        // l += P @ maskvec (broadcast ds_reads; v8-proven semantics)
        {
            bf16x8 mb0 = ldfrag(&Mbf[kc + kbase + half * 8]);
            bf16x8 mb1 = ldfrag(&Mbf[kc + kbase + 16 + half * 8]);
            lacc = __builtin_amdgcn_mfma_f32_32x32x16_bf16(pa0, mb0, lacc, 0, 0, 0);
            lacc = __builtin_amdgcn_mfma_f32_32x32x16_bf16(pa1, mb1, lacc, 0, 0, 0);
        }

        // O += P @ V   (masked V cols are zero)
        #pragma unroll
        for (int nt = 0; nt < 2; ++nt) {
            const int drow = nt * 32 + l31;
            const int kb0 = kh * 4 + half;
            const int kb1 = kh * 4 + 2 + half;
            bf16x8 vb0 = ldfrag(&Vb[drow * 64 + (kb0 ^ sw7) * 8]);
            bf16x8 vb1 = ldfrag(&Vb[drow * 64 + (kb1 ^ sw7) * 8]);
            O[nt] = __builtin_amdgcn_mfma_f32_32x32x16_bf16(pa0, vb0, O[nt], 0, 0, 0);
            O[nt] = __builtin_amdgcn_mfma_f32_32x32x16_bf16(pa1, vb1, O[nt], 0, 0, 0);
        }
        __builtin_amdgcn_s_setprio(0);
        cur ^= 1;
    }

    // combine key-halves; O scratch overlays smem (8192 f32, XOR-slotted);
    // l goes through scrl (lacc is col-broadcast -> one lane per (wv,half)).
    __syncthreads();
    float* scr = (float*)smem;
    const int sbase = (qw * 64 + lane) * 32;
    if (kh == 1) {
        #pragma unroll
        for (int j = 0; j < 4; ++j) {
            f32x4 t0, t1;
            #pragma unroll
            for (int r = 0; r < 4; ++r) { t0[r] = O[0][j * 4 + r]; t1[r] = O[1][j * 4 + r]; }
            *(f32x4*)&scr[sbase + (j ^ sw7) * 4]       = t0;
            *(f32x4*)&scr[sbase + ((j + 4) ^ sw7) * 4] = t1;
        }
        if (l31 == 0) {
            #pragma unroll
            for (int i = 0; i < 16; ++i)
                scrl[qw * 32 + half * 16 + i] = lacc[i];
        }
    }
    __syncthreads();
    if (kh == 0) {
        #pragma unroll
        for (int nt = 0; nt < 2; ++nt) {
            #pragma unroll
            for (int j = 0; j < 4; ++j) {
                const f32x4 p = *(const f32x4*)&scr[sbase + (((nt * 4 + j) ^ sw7)) * 4];
                #pragma unroll
                for (int r = 0; r < 4; ++r) {
                    const int i  = j * 4 + r;
                    const int ql = (i & 3) + 8 * (i >> 2) + 4 * half;
                    const float lt = lacc[i] + scrl[qw * 32 + half * 16 + i];
                    const float o  = O[nt][i] + p[r];
                    const int q = q0 + ql;
                    const int e = h * DH_ + nt * 32 + l31;
                    ctx[((size_t)b * S_ + q) * E_ + e] = f2bf(o / lt);
                }
            }
        }
    }
}

// ---------------------------------------------------------------------------
// Fallback tier kernels (r6/r7, proven, unchanged)
// ---------------------------------------------------------------------------
__global__ __launch_bounds__(256)
void gemm_bias(const void* __restrict__ A, int a_f32,
               const float* __restrict__ W, const float* __restrict__ bias,
               void* __restrict__ C, int c_f32,
               int M, int N, int K, float scale)
{
    __shared__ alignas(16) u16 As[64 * 32];
    __shared__ alignas(16) u16 Wt[64 * 32];
    const int tid  = threadIdx.x;
    const int lane = tid & 63;
    const int wv   = tid >> 6;
    const int l15  = lane & 15;
    const int quad = lane >> 4;
    const int m0 = blockIdx.y * 64, n0 = blockIdx.x * 64;
    const int wr = (wv >> 1) * 32, wc = (wv & 1) * 32;
    const int ar = tid >> 2, ac = (tid & 3) * 8;
    const int wk = tid >> 3, wn = (tid & 7) * 8;
    f32x4 acc[2][2] = {};
    for (int k0 = 0; k0 < K; k0 += 32) {
        __syncthreads();
        if (a_f32) {
            const float* Af = (const float*)A;
            const float* p = &Af[(size_t)(m0 + ar) * K + k0 + ac];
            float4 f0 = *(const float4*)p; float4 f1 = *(const float4*)(p + 4);
            u16x8 t;
            t[0] = f2bf(f0.x); t[1] = f2bf(f0.y); t[2] = f2bf(f0.z); t[3] = f2bf(f0.w);
            t[4] = f2bf(f1.x); t[5] = f2bf(f1.y); t[6] = f2bf(f1.z); t[7] = f2bf(f1.w);
            *(u16x8*)&As[ar * 32 + ac] = t;
        } else {
            const u16* Ab = (const u16*)A;
            *(u16x8*)&As[ar * 32 + ac] = *(const u16x8*)&Ab[(size_t)(m0 + ar) * K + k0 + ac];
        }
        {
            const float* p = &W[(size_t)(k0 + wk) * N + n0 + wn];
            float4 g0 = *(const float4*)p; float4 g1 = *(const float4*)(p + 4);
            float fv[8] = {g0.x, g0.y, g0.z, g0.w, g1.x, g1.y, g1.z, g1.w};
            #pragma unroll
            for (int j = 0; j < 8; ++j) Wt[(wn + j) * 32 + wk] = f2bf(fv[j]);
        }
        __syncthreads();
        bf16x8 a[2], b[2];
        #pragma unroll
        for (int sm = 0; sm < 2; ++sm) a[sm] = ldfrag(&As[(wr + sm * 16 + l15) * 32 + quad * 8]);
        #pragma unroll
        for (int sn = 0; sn < 2; ++sn) b[sn] = ldfrag(&Wt[(wc + sn * 16 + l15) * 32 + quad * 8]);
        #pragma unroll
        for (int sm = 0; sm < 2; ++sm)
            #pragma unroll
            for (int sn = 0; sn < 2; ++sn)
                acc[sm][sn] = __builtin_amdgcn_mfma_f32_16x16x32_bf16(a[sm], b[sn], acc[sm][sn], 0, 0, 0);
    }
    #pragma unroll
    for (int sm = 0; sm < 2; ++sm)
        #pragma unroll
        for (int sn = 0; sn < 2; ++sn) {
            const int col = n0 + wc + sn * 16 + l15;
            const float bcol = bias[col];
            #pragma unroll
            for (int r = 0; r < 4; ++r) {
                const int row = m0 + wr + sm * 16 + quad * 4 + r;
                const float v = (acc[sm][sn][r] + bcol) * scale;
                if (c_f32) ((float*)C)[(size_t)row * N + col] = v;
                else       ((u16*)C)[(size_t)row * N + col]  = f2bf(v);
            }
        }
}

__global__ __launch_bounds__(256)
void attn_v2(const u16* __restrict__ Q, const u16* __restrict__ K,
             const u16* __restrict__ V, const int* __restrict__ mask,
             u16* __restrict__ ctx, int BH_per_B)
{
    __shared__ alignas(16) u16 Ks[64 * 72];
    __shared__ alignas(16) u16 Vt[64 * 72];
    __shared__ alignas(16) u16 Pb[4][16 * 72];
    const int tid  = threadIdx.x;
    const int lane = tid & 63;
    const int wv   = tid >> 6;
    const int l15  = lane & 15;
    const int quad = lane >> 4;
    const int qt = blockIdx.x;
    const int bh = blockIdx.y;
    const int b  = bh / BH_per_B, h = bh % BH_per_B;
    const size_t headoff = (size_t)b * S_ * E_ + (size_t)h * DH_;
    const int qrow = qt * 64 + wv * 16 + l15;
    const bf16x8 qf0 = ldfrag(&Q[headoff + (size_t)qrow * E_ + quad * 8]);
    const bf16x8 qf1 = ldfrag(&Q[headoff + (size_t)qrow * E_ + 32 + quad * 8]);
    f32x4 oacc[4] = {};
    float mrun[4] = {-1e30f, -1e30f, -1e30f, -1e30f};
    float lrun[4] = {0.f, 0.f, 0.f, 0.f};
    const int skey = tid >> 2;
    const int sd0  = (tid & 3) * 16;
    for (int kc = 0; kc < S_; kc += 64) {
        __syncthreads();
        {
            const u16* kg = &K[headoff + (size_t)(kc + skey) * E_ + sd0];
            *(u16x8*)&Ks[skey * 72 + sd0]     = *(const u16x8*)kg;
            *(u16x8*)&Ks[skey * 72 + sd0 + 8] = *(const u16x8*)(kg + 8);
            const u16* vg = &V[headoff + (size_t)(kc + skey) * E_ + sd0];
            u16x8 v0 = *(const u16x8*)vg;
            u16x8 v1 = *(const u16x8*)(vg + 8);
            #pragma unroll
            for (int j = 0; j < 8; ++j) {
                const int d = sd0 + j;
                Vt[d * 72 + (skey ^ (((d >> 3) & 7) * 8))] = v0[j];
            }
            #pragma unroll
            for (int j = 0; j < 8; ++j) {
                const int d = sd0 + 8 + j;
                Vt[d * 72 + (skey ^ (((d >> 3) & 7) * 8))] = v1[j];
            }
        }
        __syncthreads();
        f32x4 sb[4];
        #pragma unroll
        for (int t = 0; t < 4; ++t) {
            bf16x8 kf0 = ldfrag(&Ks[(t * 16 + l15) * 72 + quad * 8]);
            bf16x8 kf1 = ldfrag(&Ks[(t * 16 + l15) * 72 + 32 + quad * 8]);
            f32x4 s = {};
            s = __builtin_amdgcn_mfma_f32_16x16x32_bf16(qf0, kf0, s, 0, 0, 0);
            s = __builtin_amdgcn_mfma_f32_16x16x32_bf16(qf1, kf1, s, 0, 0, 0);
            const int mv = mask[b * S_ + kc + t * 16 + l15];
            #pragma unroll
            for (int r = 0; r < 4; ++r) sb[t][r] = (mv == 0) ? -1e9f : s[r];
        }
        #pragma unroll
        for (int r = 0; r < 4; ++r) {
            float m = fmaxf(fmaxf(sb[0][r], sb[1][r]), fmaxf(sb[2][r], sb[3][r]));
            #pragma unroll
            for (int off = 1; off < 16; off <<= 1) m = fmaxf(m, __shfl_xor(m, off));
            const float mnew  = fmaxf(mrun[r], m);
            const float alpha = __expf(mrun[r] - mnew);
            mrun[r] = mnew;
            float sum = 0.f;
            #pragma unroll
            for (int t = 0; t < 4; ++t) {
                const float p = __expf(sb[t][r] - mnew);
                sb[t][r] = p; sum += p;
            }
            #pragma unroll
            for (int off = 1; off < 16; off <<= 1) sum += __shfl_xor(sum, off);
            lrun[r] = lrun[r] * alpha + sum;
            #pragma unroll
            for (int c = 0; c < 4; ++c) oacc[c][r] *= alpha;
        }
        #pragma unroll
        for (int t = 0; t < 4; ++t)
            #pragma unroll
            for (int r = 0; r < 4; ++r)
                Pb[wv][(quad * 4 + r) * 72 + t * 16 + l15] = f2bf(sb[t][r]);
        const bf16x8 pa0 = ldfrag(&Pb[wv][l15 * 72 + quad * 8]);
        const bf16x8 pa1 = ldfrag(&Pb[wv][l15 * 72 + 32 + quad * 8]);
        #pragma unroll
        for (int c = 0; c < 4; ++c) {
            const int d = c * 16 + l15;
            const int sg = ((d >> 3) & 7) * 8;
            bf16x8 vb0 = ldfrag(&Vt[d * 72 + ((quad * 8) ^ sg)]);
            bf16x8 vb1 = ldfrag(&Vt[d * 72 + ((32 + quad * 8) ^ sg)]);
            oacc[c] = __builtin_amdgcn_mfma_f32_16x16x32_bf16(pa0, vb0, oacc[c], 0, 0, 0);
            oacc[c] = __builtin_amdgcn_mfma_f32_16x16x32_bf16(pa1, vb1, oacc[c], 0, 0, 0);
        }
    }
    #pragma unroll
    for (int c = 0; c < 4; ++c) {
        const int e = h * DH_ + c * 16 + l15;
        #pragma unroll
        for (int r = 0; r < 4; ++r) {
            const int qg = qt * 64 + wv * 16 + quad * 4 + r;
            ctx[((size_t)b * S_ + qg) * E_ + e] = f2bf(oacc[c][r] / lrun[r]);
        }
    }
}

// ---------------------------------------------------------------------------
extern "C" void kernel_launch(void* const* d_in, const int* in_sizes, int n_in,
                              void* d_out, int out_size, void* d_ws, size_t ws_size,
                              hipStream_t stream)
{
    const float* query = (const float*)d_in[0];
    const float* key   = (const float*)d_in[1];
    const float* value = (const float*)d_in[2];
    const int*   mask  = (const int*)d_in[3];
    const float* Wq = (const float*)d_in[4];  const float* bq = (const float*)d_in[5];
    const float* Wk = (const float*)d_in[6];  const float* bk = (const float*)d_in[7];
    const float* Wv = (const float*)d_in[8];  const float* bv = (const float*)d_in[9];
    const float* Wo = (const float*)d_in[10]; const float* bo = (const float*)d_in[11];
    float* out = (float*)d_out;

    u16* ws = (u16*)d_ws;
    dim3 blk(256);

    const size_t need_fancy = (size_t)(6 * MELEMS + 4 * WE) * sizeof(u16);  // 58.7 MB
    const size_t need_full  = (size_t)(4 * MELEMS) * sizeof(u16) + 64;      // 33.6 MB

    if (ws_size >= need_fancy) {
        u16* Qi  = ws;                 // Cp alias (staging region unused now)
        u16* Wqt = ws + 3 * (size_t)MELEMS;
        u16* Wkt = Wqt + WE;
        u16* Wvt = Wkt + WE;
        u16* Wot = Wvt + WE;
        u16* Qp  = Wot + WE;
        u16* Kp  = Qp + MELEMS;
        u16* Vp  = Kp + MELEMS;   // holds V^T [B][E][S], masked cols zeroed
        u16* Cp  = Qi;

        cvt_w<<<dim3(1024), blk, 0, stream>>>(Wq, Wk, Wv, Wo,
                                              Wqt, Wkt, Wvt, Wot);

        // Q scale folds softmax's 1/sqrt(DH) AND log2(e) (attn uses exp2).
        // A operands are RAW fp32 inputs; conversion fused into staging
        // with counted-vmcnt barriers + double-buffered B (v22).
        gemm_bt<128, 1><<<dim3(8, 32, 3), blk, 0, stream>>>(
            query, key, value, Wqt, Wkt, Wvt, bq, bk, bv,
            Qp, Kp, Vp, mask, 0, /*vt_z=*/2, 0.125f * 1.44269504f, E_);

        attn_v15<<<dim3(S_ / 128, B_ * H_), dim3(512), 0, stream>>>(
            Qp, Kp, Vp, mask, Cp);

        // output GEMM: BN=64 (512 blocks, 2/CU) + v21 dbuf counted-vmcnt
        gemm_bt<64, 0><<<dim3(16, 32, 1), blk, 0, stream>>>(
            Cp, Cp, Cp, Wot, Wot, Wot, bo, bo, bo,
            out, out, out, mask, 1, /*vt_z=*/-1, 1.0f, E_);
    } else if (ws_size >= need_full) {
        u16* Qp = ws;
        u16* Kp = ws + MELEMS;
        u16* Vp = ws + 2 * MELEMS;
        u16* Cp = ws + 3 * MELEMS;
        const int M = B_ * S_;
        dim3 gg(E_ / 64, M / 64);
        gemm_bias<<<gg, blk, 0, stream>>>(query, 1, Wq, bq, Qp, 0, M, E_, E_, 0.125f);
        gemm_bias<<<gg, blk, 0, stream>>>(key,   1, Wk, bk, Kp, 0, M, E_, E_, 1.0f);
        gemm_bias<<<gg, blk, 0, stream>>>(value, 1, Wv, bv, Vp, 0, M, E_, E_, 1.0f);
        attn_v2<<<dim3(S_ / 64, B_ * H_), blk, 0, stream>>>(Qp, Kp, Vp, mask, Cp, H_);
        gemm_bias<<<gg, blk, 0, stream>>>(Cp, 0, Wo, bo, out, 1, M, E_, E_, 1.0f);
    } else {
        const size_t szb = (size_t)S_ * E_;
        u16* Qp = ws; u16* Kp = ws + szb; u16* Vp = ws + 2 * szb; u16* Cp = ws + 3 * szb;
        dim3 gg(E_ / 64, S_ / 64);
        for (int b = 0; b < B_; ++b) {
            gemm_bias<<<gg, blk, 0, stream>>>(query + b * szb, 1, Wq, bq, Qp, 0, S_, E_, E_, 0.125f);
            gemm_bias<<<gg, blk, 0, stream>>>(key   + b * szb, 1, Wk, bk, Kp, 0, S_, E_, E_, 1.0f);
            gemm_bias<<<gg, blk, 0, stream>>>(value + b * szb, 1, Wv, bv, Vp, 0, S_, E_, E_, 1.0f);
            attn_v2<<<dim3(S_ / 64, H_), blk, 0, stream>>>(Qp, Kp, Vp, mask + b * S_, Cp, H_);
            gemm_bias<<<gg, blk, 0, stream>>>(Cp, 0, Wo, bo, ((float*)d_out) + b * szb, 1, S_, E_, E_, 1.0f);
        }
    }
}

// Round 28
// 131.843 us; speedup vs baseline: 1.0018x; 1.0011x over previous
//
#include <hip/hip_runtime.h>
#include <hip/hip_bf16.h>
#include <stdint.h>

#define B_ 2
#define S_ 2048
#define E_ 1024
#define H_ 16
#define DH_ 64
#define MELEMS (4096 * 1024)   // B*S*E
#define WE (1024 * 1024)

typedef unsigned short u16;
typedef __bf16 bf16x8 __attribute__((ext_vector_type(8)));
typedef u16 u16x8 __attribute__((ext_vector_type(8)));
typedef u16 u16x4 __attribute__((ext_vector_type(4)));
typedef float f32x4 __attribute__((ext_vector_type(4)));
typedef float f32x16 __attribute__((ext_vector_type(16)));
typedef uint32_t u32x4 __attribute__((ext_vector_type(4)));
typedef uint32_t u32x2v __attribute__((ext_vector_type(2)));

__device__ __forceinline__ float bf2f(u16 u) {
    union { uint32_t i; float f; } v; v.i = ((uint32_t)u) << 16; return v.f;
}
__device__ __forceinline__ u16 f2bf(float f) {   // RNE fp32->bf16
    union { float f; uint32_t i; } v; v.f = f;
    uint32_t r = (v.i + 0x7FFFu + ((v.i >> 16) & 1u)) >> 16;
    return (u16)r;
}
// single-instruction packed f32x2 -> bf16x2 (RNE, same results as f2bf)
__device__ __forceinline__ uint32_t cvtpk(float a, float b) {
    uint32_t r;
    asm("v_cvt_pk_bf16_f32 %0, %1, %2" : "=v"(r) : "v"(a), "v"(b));
    return r;
}
__device__ __forceinline__ bf16x8 ldfrag(const u16* p) {
    u16x8 t = *(const u16x8*)p;
    return __builtin_bit_cast(bf16x8, t);
}
__device__ __forceinline__ void gld16(const void* g, void* l) {
    __builtin_amdgcn_global_load_lds(
        (const __attribute__((address_space(1))) void*)g,
        (__attribute__((address_space(3))) void*)l, 16, 0, 0);
}

// ---------------------------------------------------------------------------
// Weight transpose only: W[K][N] fp32 -> Wt[N][K] bf16 (LDS-tiled, 65-stride).
// ---------------------------------------------------------------------------
__global__ __launch_bounds__(256)
void cvt_w(const float* __restrict__ W0, const float* __restrict__ W1,
           const float* __restrict__ W2, const float* __restrict__ W3,
           u16* __restrict__ T0, u16* __restrict__ T1,
           u16* __restrict__ T2, u16* __restrict__ T3)
{
    __shared__ float tile[64][65];
    const int rr = blockIdx.x;          // 0..1023
    const int tid = threadIdx.x;
    const int z = rr >> 8;
    const int tt = rr & 255;
    const float* W = (z == 0) ? W0 : (z == 1) ? W1 : (z == 2) ? W2 : W3;
    u16* T = (z == 0) ? T0 : (z == 1) ? T1 : (z == 2) ? T2 : T3;
    const int n0 = (tt & 15) * 64, k0 = (tt >> 4) * 64;
    const int r = tid >> 2, c0 = (tid & 3) * 16;

    #pragma unroll
    for (int i = 0; i < 4; ++i) {
        float4 w = *(const float4*)&W[(size_t)(k0 + r) * 1024 + n0 + c0 + i * 4];
        tile[r][c0 + i * 4 + 0] = w.x; tile[r][c0 + i * 4 + 1] = w.y;
        tile[r][c0 + i * 4 + 2] = w.z; tile[r][c0 + i * 4 + 3] = w.w;
    }
    __syncthreads();
    u16x8 a, b;
    #pragma unroll
    for (int j = 0; j < 8; ++j) a[j] = f2bf(tile[c0 + j][r]);
    #pragma unroll
    for (int j = 0; j < 8; ++j) b[j] = f2bf(tile[c0 + 8 + j][r]);
    *(u16x8*)&T[(size_t)(n0 + r) * 1024 + k0 + c0] = a;
    *(u16x8*)&T[(size_t)(n0 + r) * 1024 + k0 + c0 + 8] = b;
}

// ---------------------------------------------------------------------------
// m97-style GEMM: C = (A[M,K] @ Bt[N,K]^T + bias[N]) * scale.
// AF32=1 (v22-proven): A fp32 fused conversion + DOUBLE-BUFFERED B, counted
//   vmcnt: per iter: lgkmcnt(0)+barrier -> cvtpk A (compiler's A-reg wait
//   drains the OLDER current-B gld16s: B always issued before A) -> issue
//   B(k+32)->Bs[cur^1] -> loadA(k+32) -> ds_write As -> vmcnt(6)+lgkmcnt(0)
//   (6 newest = next-B 2 + next-A 4 in flight; current B older -> landed)
//   -> barrier -> 16 MFMAs.  B-latency cover: full iteration (~800 cyc).
// AF32=0 (v21-proven): double-buffered counted-vmcnt tile staging.
// z==vt_z: writes V^T [B][E][S] with masked key COLUMNS zeroed.
// XCD-chunked block swizzle (T1).
// ---------------------------------------------------------------------------
template<int BN, int AF32>
__global__ __launch_bounds__(256)
void gemm_bt(const void* __restrict__ A0, const void* __restrict__ A1,
             const void* __restrict__ A2,
             const u16* __restrict__ Bt0, const u16* __restrict__ Bt1,
             const u16* __restrict__ Bt2,
             const float* __restrict__ b0, const float* __restrict__ b1,
             const float* __restrict__ b2,
             void* __restrict__ C0, void* __restrict__ C1, void* __restrict__ C2,
             const int* __restrict__ mask,
             int c_f32, int vt_z, float scale0, int K)
{
    const int z = blockIdx.z;
    const void* Av = (z == 0) ? A0 : (z == 1) ? A1 : A2;
    const u16* Bt = (z == 0) ? Bt0 : (z == 1) ? Bt1 : Bt2;
    const float* bias = (z == 0) ? b0 : (z == 1) ? b1 : b2;
    void* C = (z == 0) ? C0 : (z == 1) ? C1 : C2;
    const float scale = (z == 0) ? scale0 : 1.0f;

    // AF32=1: A single-buffered (arrives via regs), B double.  AF32=0: both double.
    __shared__ alignas(16) u16 As[(AF32 ? 1 : 2) * 128 * 32];
    __shared__ alignas(16) u16 Bs[2 * BN * 32];

    const int tid  = threadIdx.x;
    const int lane = tid & 63;
    const int wv   = tid >> 6;
    const int l15  = lane & 15;
    const int quad = lane >> 4;

    // XCD-chunked remap within this z-slice
    const int nwg = gridDim.x * gridDim.y;
    int wg = blockIdx.y * gridDim.x + blockIdx.x;
    wg = (wg & 7) * (nwg >> 3) + (wg >> 3);
    const int bx = wg % gridDim.x;
    const int by = wg / gridDim.x;

    const int m0 = by * 128;
    const int n0 = bx * BN;
    const int wr = (wv >> 1) * 64;
    const int wc = (wv & 1) * (BN / 2);

    const int srow = wv * 16 + (lane >> 2);
    const int skk  = (lane & 3) * 8;

    constexpr int NJ = BN / 32;
    f32x4 acc[4][NJ] = {};

    float4 ar0, ar1, ar2, ar3;      // AF32 staging regs (2 rows x 32B)
    auto loadA = [&](int k0) {
        const float* Af = (const float*)Av;
        const float* p0 = &Af[(size_t)(m0 + srow) * K + k0 + skk];
        const float* p1 = &Af[(size_t)(m0 + 64 + srow) * K + k0 + skk];
        ar0 = *(const float4*)p0;  ar1 = *(const float4*)(p0 + 4);
        ar2 = *(const float4*)p1;  ar3 = *(const float4*)(p1 + 4);
    };
    // stage B tile into buffer `buf` (BN/64 gld16 per thread)
    auto stageB = [&](int k0, int buf) {
        const int bo = buf * (BN * 32);
        #pragma unroll
        for (int h = 0; h < BN / 64; ++h) {
            const int r = h * 64 + srow;
            gld16(&Bt[(size_t)(n0 + r) * K + k0 + skk], &Bs[bo + r * 32 + skk]);
        }
    };
    // AF32=0: stage one full tile (A 2x + B) into buffer `buf`
    auto stageT = [&](int k0, int buf) {
        const u16* Ab = (const u16*)Av;
        const int ao = buf * (128 * 32);
        #pragma unroll
        for (int h = 0; h < 2; ++h) {
            const int r = h * 64 + srow;
            gld16(&Ab[(size_t)(m0 + r) * K + k0 + skk], &As[ao + r * 32 + skk]);
        }
        stageB(k0, buf);
    };

    if (AF32) {
        stageB(0, 0);                 // B first (oldest in FIFO)
        asm volatile("" ::: "memory");
        loadA(0);
        asm volatile("" ::: "memory");
    } else {
        stageT(0, 0);
        asm volatile("" ::: "memory");
    }

    int cur = 0;
    for (int k0 = 0; k0 < K; k0 += 32) {
        if (AF32) {
            // top barrier: ds-reads done; in-flight loads survive
            asm volatile("s_waitcnt lgkmcnt(0)" ::: "memory");
            __builtin_amdgcn_s_barrier();
            asm volatile("" ::: "memory");
            // pack current A; compiler's wait for the A regs also drains the
            // OLDER current-B gld16s (B always issued before A) -> Bs[cur] ok
            u32x4 w0, w1;
            w0[0] = cvtpk(ar0.x, ar0.y); w0[1] = cvtpk(ar0.z, ar0.w);
            w0[2] = cvtpk(ar1.x, ar1.y); w0[3] = cvtpk(ar1.z, ar1.w);
            w1[0] = cvtpk(ar2.x, ar2.y); w1[1] = cvtpk(ar2.z, ar2.w);
            w1[2] = cvtpk(ar3.x, ar3.y); w1[3] = cvtpk(ar3.z, ar3.w);
            asm volatile("" ::: "memory");
            // next-B first (stays in flight across the barrier below) ...
            if (k0 + 32 < K) stageB(k0 + 32, cur ^ 1);
            asm volatile("" ::: "memory");
            // ... then next A
            if (k0 + 32 < K) loadA(k0 + 32);
            asm volatile("" ::: "memory");
            *(u32x4*)&As[srow * 32 + skk]        = w0;
            *(u32x4*)&As[(64 + srow) * 32 + skk] = w1;
            if (k0 + 32 < K)
                asm volatile("s_waitcnt vmcnt(6) lgkmcnt(0)" ::: "memory");
            else
                asm volatile("s_waitcnt vmcnt(0) lgkmcnt(0)" ::: "memory");
            __builtin_amdgcn_s_barrier();
            asm volatile("" ::: "memory");
        } else {
            // barrier 1: previous iter's ds-reads of buf^1 are complete
            asm volatile("s_waitcnt lgkmcnt(0)" ::: "memory");
            __builtin_amdgcn_s_barrier();
            asm volatile("" ::: "memory");
            if (k0 + 32 < K) {
                stageT(k0 + 32, cur ^ 1);     // overwrite-safe after barrier
                asm volatile("" ::: "memory");
                // tile cur's 3 loads are oldest -> <=3 outstanding => landed
                if constexpr (BN == 64)
                    asm volatile("s_waitcnt vmcnt(3)" ::: "memory");
                else
                    asm volatile("s_waitcnt vmcnt(0)" ::: "memory");
            } else {
                asm volatile("s_waitcnt vmcnt(0)" ::: "memory");
            }
            __builtin_amdgcn_s_barrier();
            asm volatile("" ::: "memory");
        }

        const int ao = AF32 ? 0 : cur * (128 * 32);
        const int bo = cur * (BN * 32);
        bf16x8 a[4], b[NJ];
        #pragma unroll
        for (int i = 0; i < 4; ++i)
            a[i] = ldfrag(&As[ao + (wr + i * 16 + l15) * 32 + quad * 8]);
        #pragma unroll
        for (int j = 0; j < NJ; ++j)
            b[j] = ldfrag(&Bs[bo + (wc + j * 16 + l15) * 32 + quad * 8]);
        #pragma unroll
        for (int i = 0; i < 4; ++i)
            #pragma unroll
            for (int j = 0; j < NJ; ++j)
                acc[i][j] = __builtin_amdgcn_mfma_f32_16x16x32_bf16(
                    a[i], b[j], acc[i][j], 0, 0, 0);
        cur ^= 1;
    }

    #pragma unroll
    for (int j = 0; j < NJ; ++j) {
        const int col = n0 + wc + j * 16 + l15;
        const float bcol = bias[col];
        #pragma unroll
        for (int i = 0; i < 4; ++i) {
            const int row0 = m0 + wr + i * 16 + quad * 4;
            if (z == vt_z) {
                const int bb = row0 >> 11, s0 = row0 & 2047;
                const int4 mv = *(const int4*)&mask[bb * S_ + s0];
                u16x4 t;
                t[0] = mv.x ? f2bf((acc[i][j][0] + bcol) * scale) : (u16)0;
                t[1] = mv.y ? f2bf((acc[i][j][1] + bcol) * scale) : (u16)0;
                t[2] = mv.z ? f2bf((acc[i][j][2] + bcol) * scale) : (u16)0;
                t[3] = mv.w ? f2bf((acc[i][j][3] + bcol) * scale) : (u16)0;
                *(u16x4*)&((u16*)C)[((size_t)bb * E_ + col) * S_ + s0] = t;
            } else {
                #pragma unroll
                for (int r = 0; r < 4; ++r) {
                    const int row = row0 + r;
                    const float v = (acc[i][j][r] + bcol) * scale;
                    if (c_f32) ((float*)C)[(size_t)row * 1024 + col] = v;
                    else       ((u16*)C)[(size_t)row * 1024 + col]  = f2bf(v);
                }
            }
        }
    }
}

// ---------------------------------------------------------------------------
// Flash attention v15 (proven 63.8us): v12 + XCD-chunked block swizzle.
// ---------------------------------------------------------------------------
__global__ __launch_bounds__(512, 4)
void attn_v15(const u16* __restrict__ Q, const u16* __restrict__ K,
              const u16* __restrict__ Vt_g, const int* __restrict__ mask,
              u16* __restrict__ ctx)
{
    // per buffer 8192 u16: K 64x64 at [0], V(d-major) 64x64 at [4096]
    __shared__ alignas(16) u16 smem[2][8192];
    __shared__ alignas(16) u16 Mbf[S_];      // bf16 {0,1} mask table (4KB)
    __shared__ float scrl[256];

    const int tid  = threadIdx.x;
    const int lane = tid & 63;
    const int wv   = tid >> 6;          // 0..7
    const int l31  = lane & 31;
    const int half = lane >> 5;
    const int sw7  = lane & 7;
    const int qw   = wv & 3;            // q-strip (32 rows)
    const int kh   = wv >> 2;           // key-half of the 64-key chunk
    const int kbase = kh * 32;

    // XCD-chunked remap: XCD r -> bh in [4r, 4r+4), all 16 qt
    const int nwg = gridDim.x * gridDim.y;     // 512
    int wg = blockIdx.y * gridDim.x + blockIdx.x;
    wg = (wg & 7) * (nwg >> 3) + (wg >> 3);
    const int qt = wg % gridDim.x;             // gridDim.x = 16
    const int bh = wg / gridDim.x;
    const int b  = bh >> 4, h = bh & 15;

    const size_t qk_off = (size_t)b * S_ * E_ + (size_t)h * DH_;
    const size_t vt_off = ((size_t)b * E_ + (size_t)h * DH_) * S_;
    const int* mrow = &mask[b * S_];

    // one-time: mask -> bf16 multiplier table (visible after first barrier)
    {
        const int i = tid * 4;
        const int4 m = *(const int4*)&mrow[i];
        u16x4 t;
        t[0] = m.x ? (u16)0x3F80 : (u16)0;
        t[1] = m.y ? (u16)0x3F80 : (u16)0;
        t[2] = m.z ? (u16)0x3F80 : (u16)0;
        t[3] = m.w ? (u16)0x3F80 : (u16)0;
        *(u16x4*)&Mbf[i] = t;
    }

    // Q B-fragments (col = q = l31, k = d), loop-invariant
    const int q0 = qt * 128 + qw * 32;
    bf16x8 qf[4];
    #pragma unroll
    for (int s = 0; s < 4; ++s)
        qf[s] = ldfrag(&Q[qk_off + (size_t)(q0 + l31) * E_ + s * 16 + half * 8]);

    f32x16 O[2] = {};   // [d-tile]  rows = q-local, col = d = l31
    f32x16 lacc = {};   // l partial, same row mapping (col-broadcast)

    // staging: 1 K-gld16 + 1 V-gld16 per thread per chunk; XOR placement
    auto stage = [&](int kc, int buf) {
        const int rr = tid >> 3;              // key (K) / d-row (V), 0..63
        const int ks = tid & 7;               // LDS slot
        const int gb = ks ^ (rr & 7);         // global 8-elem block
        gld16(&K[qk_off + (size_t)(kc + rr) * E_ + gb * 8],
              &smem[buf][rr * 64 + ks * 8]);
        gld16(&Vt_g[vt_off + (size_t)rr * S_ + kc + gb * 8],
              &smem[buf][4096 + rr * 64 + ks * 8]);
    };

    stage(0, 0);
    int cur = 0;

    for (int kc = 0; kc < S_; kc += 64) {
        __syncthreads();                 // drains gld16s -> buf[cur] ready
        if (kc + 64 < S_) stage(kc + 64, cur ^ 1);
        const u16* Kb = &smem[cur][0];
        const u16* Vb = &smem[cur][4096];

        // St[key][q] for this wave-group's 32 keys
        __builtin_amdgcn_s_setprio(1);
        f32x16 St = {};
        #pragma unroll
        for (int s = 0; s < 4; ++s) {
            bf16x8 kf = ldfrag(&Kb[(kbase + l31) * 64 + ((s * 2 + half) ^ sw7) * 8]);
            St = __builtin_amdgcn_mfma_f32_32x32x16_bf16(kf, qf[s], St, 0, 0, 0);
        }
        __builtin_amdgcn_s_setprio(0);
        float ex[16];
        #pragma unroll
        for (int i = 0; i < 16; ++i) ex[i] = __builtin_exp2f(St[i]);

        // pack to bf16 (the values PV and l will consume)
        uint32_t wd[8];
        #pragma unroll
        for (int i = 0; i < 8; ++i) wd[i] = cvtpk(ex[2 * i], ex[2 * i + 1]);

        // permlane32_swap -> A-frags in natural key order
        u32x2v r02 = __builtin_amdgcn_permlane32_swap(wd[0], wd[2], false, false);
        u32x2v r13 = __builtin_amdgcn_permlane32_swap(wd[1], wd[3], false, false);
        u32x2v r46 = __builtin_amdgcn_permlane32_swap(wd[4], wd[6], false, false);
        u32x2v r57 = __builtin_amdgcn_permlane32_swap(wd[5], wd[7], false, false);
        u32x4 f0, f1;
        f0[0] = r02[0]; f0[1] = r13[0]; f0[2] = r02[1]; f0[3] = r13[1];
        f1[0] = r46[0]; f1[1] = r57[0]; f1[2] = r46[1]; f1[3] = r57[1];
        const bf16x8 pa0 = __builtin_bit_cast(bf16x8, f0);  // keys kbase+0..15
        const bf16x8 pa1 = __builtin_bit_cast(bf16x8, f1);  // keys kbase+16..31

        __builtin_amdgcn_s_setprio(1);
        // l += P @ maskvec (broadcast ds_reads; v8-proven semantics)
        {
            bf16x8 mb0 = ldfrag(&Mbf[kc + kbase + half * 8]);
            bf16x8 mb1 = ldfrag(&Mbf[kc + kbase + 16 + half * 8]);
            lacc = __builtin_amdgcn_mfma_f32_32x32x16_bf16(pa0, mb0, lacc, 0, 0, 0);
            lacc = __builtin_amdgcn_mfma_f32_32x32x16_bf16(pa1, mb1, lacc, 0, 0, 0);
        }

        // O += P @ V   (masked V cols are zero)
        #pragma unroll
        for (int nt = 0; nt < 2; ++nt) {
            const int drow = nt * 32 + l31;
            const int kb0 = kh * 4 + half;
            const int kb1 = kh * 4 + 2 + half;
            bf16x8 vb0 = ldfrag(&Vb[drow * 64 + (kb0 ^ sw7) * 8]);
            bf16x8 vb1 = ldfrag(&Vb[drow * 64 + (kb1 ^ sw7) * 8]);
            O[nt] = __builtin_amdgcn_mfma_f32_32x32x16_bf16(pa0, vb0, O[nt], 0, 0, 0);
            O[nt] = __builtin_amdgcn_mfma_f32_32x32x16_bf16(pa1, vb1, O[nt], 0, 0, 0);
        }
        __builtin_amdgcn_s_setprio(0);
        cur ^= 1;
    }

    // combine key-halves; O scratch overlays smem (8192 f32, XOR-slotted);
    // l goes through scrl (lacc is col-broadcast -> one lane per (wv,half)).
    __syncthreads();
    float* scr = (float*)smem;
    const int sbase = (qw * 64 + lane) * 32;
    if (kh == 1) {
        #pragma unroll
        for (int j = 0; j < 4; ++j) {
            f32x4 t0, t1;
            #pragma unroll
            for (int r = 0; r < 4; ++r) { t0[r] = O[0][j * 4 + r]; t1[r] = O[1][j * 4 + r]; }
            *(f32x4*)&scr[sbase + (j ^ sw7) * 4]       = t0;
            *(f32x4*)&scr[sbase + ((j + 4) ^ sw7) * 4] = t1;
        }
        if (l31 == 0) {
            #pragma unroll
            for (int i = 0; i < 16; ++i)
                scrl[qw * 32 + half * 16 + i] = lacc[i];
        }
    }
    __syncthreads();
    if (kh == 0) {
        #pragma unroll
        for (int nt = 0; nt < 2; ++nt) {
            #pragma unroll
            for (int j = 0; j < 4; ++j) {
                const f32x4 p = *(const f32x4*)&scr[sbase + (((nt * 4 + j) ^ sw7)) * 4];
                #pragma unroll
                for (int r = 0; r < 4; ++r) {
                    const int i  = j * 4 + r;
                    const int ql = (i & 3) + 8 * (i >> 2) + 4 * half;
                    const float lt = lacc[i] + scrl[qw * 32 + half * 16 + i];
                    const float o  = O[nt][i] + p[r];
                    const int q = q0 + ql;
                    const int e = h * DH_ + nt * 32 + l31;
                    ctx[((size_t)b * S_ + q) * E_ + e] = f2bf(o / lt);
                }
            }
        }
    }
}

// ---------------------------------------------------------------------------
// Fallback tier kernels (r6/r7, proven, unchanged)
// ---------------------------------------------------------------------------
__global__ __launch_bounds__(256)
void gemm_bias(const void* __restrict__ A, int a_f32,
               const float* __restrict__ W, const float* __restrict__ bias,
               void* __restrict__ C, int c_f32,
               int M, int N, int K, float scale)
{
    __shared__ alignas(16) u16 As[64 * 32];
    __shared__ alignas(16) u16 Wt[64 * 32];
    const int tid  = threadIdx.x;
    const int lane = tid & 63;
    const int wv   = tid >> 6;
    const int l15  = lane & 15;
    const int quad = lane >> 4;
    const int m0 = blockIdx.y * 64, n0 = blockIdx.x * 64;
    const int wr = (wv >> 1) * 32, wc = (wv & 1) * 32;
    const int ar = tid >> 2, ac = (tid & 3) * 8;
    const int wk = tid >> 3, wn = (tid & 7) * 8;
    f32x4 acc[2][2] = {};
    for (int k0 = 0; k0 < K; k0 += 32) {
        __syncthreads();
        if (a_f32) {
            const float* Af = (const float*)A;
            const float* p = &Af[(size_t)(m0 + ar) * K + k0 + ac];
            float4 f0 = *(const float4*)p; float4 f1 = *(const float4*)(p + 4);
            u16x8 t;
            t[0] = f2bf(f0.x); t[1] = f2bf(f0.y); t[2] = f2bf(f0.z); t[3] = f2bf(f0.w);
            t[4] = f2bf(f1.x); t[5] = f2bf(f1.y); t[6] = f2bf(f1.z); t[7] = f2bf(f1.w);
            *(u16x8*)&As[ar * 32 + ac] = t;
        } else {
            const u16* Ab = (const u16*)A;
            *(u16x8*)&As[ar * 32 + ac] = *(const u16x8*)&Ab[(size_t)(m0 + ar) * K + k0 + ac];
        }
        {
            const float* p = &W[(size_t)(k0 + wk) * N + n0 + wn];
            float4 g0 = *(const float4*)p; float4 g1 = *(const float4*)(p + 4);
            float fv[8] = {g0.x, g0.y, g0.z, g0.w, g1.x, g1.y, g1.z, g1.w};
            #pragma unroll
            for (int j = 0; j < 8; ++j) Wt[(wn + j) * 32 + wk] = f2bf(fv[j]);
        }
        __syncthreads();
        bf16x8 a[2], b[2];
        #pragma unroll
        for (int sm = 0; sm < 2; ++sm) a[sm] = ldfrag(&As[(wr + sm * 16 + l15) * 32 + quad * 8]);
        #pragma unroll
        for (int sn = 0; sn < 2; ++sn) b[sn] = ldfrag(&Wt[(wc + sn * 16 + l15) * 32 + quad * 8]);
        #pragma unroll
        for (int sm = 0; sm < 2; ++sm)
            #pragma unroll
            for (int sn = 0; sn < 2; ++sn)
                acc[sm][sn] = __builtin_amdgcn_mfma_f32_16x16x32_bf16(a[sm], b[sn], acc[sm][sn], 0, 0, 0);
    }
    #pragma unroll
    for (int sm = 0; sm < 2; ++sm)
        #pragma unroll
        for (int sn = 0; sn < 2; ++sn) {
            const int col = n0 + wc + sn * 16 + l15;
            const float bcol = bias[col];
            #pragma unroll
            for (int r = 0; r < 4; ++r) {
                const int row = m0 + wr + sm * 16 + quad * 4 + r;
                const float v = (acc[sm][sn][r] + bcol) * scale;
                if (c_f32) ((float*)C)[(size_t)row * N + col] = v;
                else       ((u16*)C)[(size_t)row * N + col]  = f2bf(v);
            }
        }
}

__global__ __launch_bounds__(256)
void attn_v2(const u16* __restrict__ Q, const u16* __restrict__ K,
             const u16* __restrict__ V, const int* __restrict__ mask,
             u16* __restrict__ ctx, int BH_per_B)
{
    __shared__ alignas(16) u16 Ks[64 * 72];
    __shared__ alignas(16) u16 Vt[64 * 72];
    __shared__ alignas(16) u16 Pb[4][16 * 72];
    const int tid  = threadIdx.x;
    const int lane = tid & 63;
    const int wv   = tid >> 6;
    const int l15  = lane & 15;
    const int quad = lane >> 4;
    const int qt = blockIdx.x;
    const int bh = blockIdx.y;
    const int b  = bh / BH_per_B, h = bh % BH_per_B;
    const size_t headoff = (size_t)b * S_ * E_ + (size_t)h * DH_;
    const int qrow = qt * 64 + wv * 16 + l15;
    const bf16x8 qf0 = ldfrag(&Q[headoff + (size_t)qrow * E_ + quad * 8]);
    const bf16x8 qf1 = ldfrag(&Q[headoff + (size_t)qrow * E_ + 32 + quad * 8]);
    f32x4 oacc[4] = {};
    float mrun[4] = {-1e30f, -1e30f, -1e30f, -1e30f};
    float lrun[4] = {0.f, 0.f, 0.f, 0.f};
    const int skey = tid >> 2;
    const int sd0  = (tid & 3) * 16;
    for (int kc = 0; kc < S_; kc += 64) {
        __syncthreads();
        {
            const u16* kg = &K[headoff + (size_t)(kc + skey) * E_ + sd0];
            *(u16x8*)&Ks[skey * 72 + sd0]     = *(const u16x8*)kg;
            *(u16x8*)&Ks[skey * 72 + sd0 + 8] = *(const u16x8*)(kg + 8);
            const u16* vg = &V[headoff + (size_t)(kc + skey) * E_ + sd0];
            u16x8 v0 = *(const u16x8*)vg;
            u16x8 v1 = *(const u16x8*)(vg + 8);
            #pragma unroll
            for (int j = 0; j < 8; ++j) {
                const int d = sd0 + j;
                Vt[d * 72 + (skey ^ (((d >> 3) & 7) * 8))] = v0[j];
            }
            #pragma unroll
            for (int j = 0; j < 8; ++j) {
                const int d = sd0 + 8 + j;
                Vt[d * 72 + (skey ^ (((d >> 3) & 7) * 8))] = v1[j];
            }
        }
        __syncthreads();
        f32x4 sb[4];
        #pragma unroll
        for (int t = 0; t < 4; ++t) {
            bf16x8 kf0 = ldfrag(&Ks[(t * 16 + l15) * 72 + quad * 8]);
            bf16x8 kf1 = ldfrag(&Ks[(t * 16 + l15) * 72 + 32 + quad * 8]);
            f32x4 s = {};
            s = __builtin_amdgcn_mfma_f32_16x16x32_bf16(qf0, kf0, s, 0, 0, 0);
            s = __builtin_amdgcn_mfma_f32_16x16x32_bf16(qf1, kf1, s, 0, 0, 0);
            const int mv = mask[b * S_ + kc + t * 16 + l15];
            #pragma unroll
            for (int r = 0; r < 4; ++r) sb[t][r] = (mv == 0) ? -1e9f : s[r];
        }
        #pragma unroll
        for (int r = 0; r < 4; ++r) {
            float m = fmaxf(fmaxf(sb[0][r], sb[1][r]), fmaxf(sb[2][r], sb[3][r]));
            #pragma unroll
            for (int off = 1; off < 16; off <<= 1) m = fmaxf(m, __shfl_xor(m, off));
            const float mnew  = fmaxf(mrun[r], m);
            const float alpha = __expf(mrun[r] - mnew);
            mrun[r] = mnew;
            float sum = 0.f;
            #pragma unroll
            for (int t = 0; t < 4; ++t) {
                const float p = __expf(sb[t][r] - mnew);
                sb[t][r] = p; sum += p;
            }
            #pragma unroll
            for (int off = 1; off < 16; off <<= 1) sum += __shfl_xor(sum, off);
            lrun[r] = lrun[r] * alpha + sum;
            #pragma unroll
            for (int c = 0; c < 4; ++c) oacc[c][r] *= alpha;
        }
        #pragma unroll
        for (int t = 0; t < 4; ++t)
            #pragma unroll
            for (int r = 0; r < 4; ++r)
                Pb[wv][(quad * 4 + r) * 72 + t * 16 + l15] = f2bf(sb[t][r]);
        const bf16x8 pa0 = ldfrag(&Pb[wv][l15 * 72 + quad * 8]);
        const bf16x8 pa1 = ldfrag(&Pb[wv][l15 * 72 + 32 + quad * 8]);
        #pragma unroll
        for (int c = 0; c < 4; ++c) {
            const int d = c * 16 + l15;
            const int sg = ((d >> 3) & 7) * 8;
            bf16x8 vb0 = ldfrag(&Vt[d * 72 + ((quad * 8) ^ sg)]);
            bf16x8 vb1 = ldfrag(&Vt[d * 72 + ((32 + quad * 8) ^ sg)]);
            oacc[c] = __builtin_amdgcn_mfma_f32_16x16x32_bf16(pa0, vb0, oacc[c], 0, 0, 0);
            oacc[c] = __builtin_amdgcn_mfma_f32_16x16x32_bf16(pa1, vb1, oacc[c], 0, 0, 0);
        }
    }
    #pragma unroll
    for (int c = 0; c < 4; ++c) {
        const int e = h * DH_ + c * 16 + l15;
        #pragma unroll
        for (int r = 0; r < 4; ++r) {
            const int qg = qt * 64 + wv * 16 + quad * 4 + r;
            ctx[((size_t)b * S_ + qg) * E_ + e] = f2bf(oacc[c][r] / lrun[r]);
        }
    }
}

// ---------------------------------------------------------------------------
extern "C" void kernel_launch(void* const* d_in, const int* in_sizes, int n_in,
                              void* d_out, int out_size, void* d_ws, size_t ws_size,
                              hipStream_t stream)
{
    const float* query = (const float*)d_in[0];
    const float* key   = (const float*)d_in[1];
    const float* value = (const float*)d_in[2];
    const int*   mask  = (const int*)d_in[3];
    const float* Wq = (const float*)d_in[4];  const float* bq = (const float*)d_in[5];
    const float* Wk = (const float*)d_in[6];  const float* bk = (const float*)d_in[7];
    const float* Wv = (const float*)d_in[8];  const float* bv = (const float*)d_in[9];
    const float* Wo = (const float*)d_in[10]; const float* bo = (const float*)d_in[11];
    float* out = (float*)d_out;

    u16* ws = (u16*)d_ws;
    dim3 blk(256);

    const size_t need_fancy = (size_t)(6 * MELEMS + 4 * WE) * sizeof(u16);  // 58.7 MB
    const size_t need_full  = (size_t)(4 * MELEMS) * sizeof(u16) + 64;      // 33.6 MB

    if (ws_size >= need_fancy) {
        u16* Qi  = ws;                 // Cp alias (staging region unused now)
        u16* Wqt = ws + 3 * (size_t)MELEMS;
        u16* Wkt = Wqt + WE;
        u16* Wvt = Wkt + WE;
        u16* Wot = Wvt + WE;
        u16* Qp  = Wot + WE;
        u16* Kp  = Qp + MELEMS;
        u16* Vp  = Kp + MELEMS;   // holds V^T [B][E][S], masked cols zeroed
        u16* Cp  = Qi;

        cvt_w<<<dim3(1024), blk, 0, stream>>>(Wq, Wk, Wv, Wo,
                                              Wqt, Wkt, Wvt, Wot);

        // Q scale folds softmax's 1/sqrt(DH) AND log2(e) (attn uses exp2).
        // A operands are RAW fp32 inputs; conversion fused into staging
        // with counted-vmcnt barriers + double-buffered B (v22).
        gemm_bt<128, 1><<<dim3(8, 32, 3), blk, 0, stream>>>(
            query, key, value, Wqt, Wkt, Wvt, bq, bk, bv,
            Qp, Kp, Vp, mask, 0, /*vt_z=*/2, 0.125f * 1.44269504f, E_);

        attn_v15<<<dim3(S_ / 128, B_ * H_), dim3(512), 0, stream>>>(
            Qp, Kp, Vp, mask, Cp);

        // output GEMM: BN=64 (512 blocks, 2/CU) + v21 dbuf counted-vmcnt
        gemm_bt<64, 0><<<dim3(16, 32, 1), blk, 0, stream>>>(
            Cp, Cp, Cp, Wot, Wot, Wot, bo, bo, bo,
            out, out, out, mask, 1, /*vt_z=*/-1, 1.0f, E_);
    } else if (ws_size >= need_full) {
        u16* Qp = ws;
        u16* Kp = ws + MELEMS;
        u16* Vp = ws + 2 * MELEMS;
        u16* Cp = ws + 3 * MELEMS;
        const int M = B_ * S_;
        dim3 gg(E_ / 64, M / 64);
        gemm_bias<<<gg, blk, 0, stream>>>(query, 1, Wq, bq, Qp, 0, M, E_, E_, 0.125f);
        gemm_bias<<<gg, blk, 0, stream>>>(key,   1, Wk, bk, Kp, 0, M, E_, E_, 1.0f);
        gemm_bias<<<gg, blk, 0, stream>>>(value, 1, Wv, bv, Vp, 0, M, E_, E_, 1.0f);
        attn_v2<<<dim3(S_ / 64, B_ * H_), blk, 0, stream>>>(Qp, Kp, Vp, mask, Cp, H_);
        gemm_bias<<<gg, blk, 0, stream>>>(Cp, 0, Wo, bo, out, 1, M, E_, E_, 1.0f);
    } else {
        const size_t szb = (size_t)S_ * E_;
        u16* Qp = ws; u16* Kp = ws + szb; u16* Vp = ws + 2 * szb; u16* Cp = ws + 3 * szb;
        dim3 gg(E_ / 64, S_ / 64);
        for (int b = 0; b < B_; ++b) {
            gemm_bias<<<gg, blk, 0, stream>>>(query + b * szb, 1, Wq, bq, Qp, 0, S_, E_, E_, 0.125f);
            gemm_bias<<<gg, blk, 0, stream>>>(key   + b * szb, 1, Wk, bk, Kp, 0, S_, E_, E_, 1.0f);
            gemm_bias<<<gg, blk, 0, stream>>>(value + b * szb, 1, Wv, bv, Vp, 0, S_, E_, E_, 1.0f);
            attn_v2<<<dim3(S_ / 64, H_), blk, 0, stream>>>(Qp, Kp, Vp, mask + b * S_, Cp, H_);
            gemm_bias<<<gg, blk, 0, stream>>>(Cp, 0, Wo, bo, ((float*)d_out) + b * szb, 1, S_, E_, E_, 1.0f);
        }
    }
}